// Round 1
// baseline (1092.073 us; speedup 1.0000x reference)
//
#include <hip/hip_runtime.h>
#include <math.h>

#define BN_EPS 1e-5f

// Problem constants
// B=16, N=1024 (32x32), DIN=768, D=512, HID=128, C=20, K=64 protos/class
// M = B*N = 16384 rows throughout; all tensors kept as [row=b*N+n][channel] (NHWC)

// ---------------------------------------------------------------------------
// Generic fp32 NT GEMM:  C[M][Nc] = A[M][K] * W[Nc][K]^T, fused epilogues.
// Tile 64x64, BK=16, 256 threads, 4x4 micro-tile per thread.
// EPI 0: BN + ReLU
// EPI 1: BN + residual add + ReLU
// EPI 2: + bias (no activation)
// ---------------------------------------------------------------------------
template <int EPI>
__global__ __launch_bounds__(256) void gemm_nt(
    const float* __restrict__ A, int lda,
    const float* __restrict__ Wt, int ldw,
    float* __restrict__ Cout, int ldc, int Kdim,
    const float* __restrict__ bng, const float* __restrict__ bnb,
    const float* __restrict__ bnm, const float* __restrict__ bnv,
    const float* __restrict__ res, int ldres,
    const float* __restrict__ bias)
{
    __shared__ float As[16][64];
    __shared__ float Ws[16][64];
    const int t  = threadIdx.x;
    const int tr = t >> 4, tc = t & 15;
    const int rA = t >> 2, kv = (t & 3) << 2;
    const int m0 = blockIdx.x << 6, n0 = blockIdx.y << 6;

    const float* Aload = A + (size_t)(m0 + rA) * lda + kv;
    const float* Wload = Wt + (size_t)(n0 + rA) * ldw + kv;

    float acc[4][4] = {};

    for (int k0 = 0; k0 < Kdim; k0 += 16) {
        float4 a4 = *(const float4*)(Aload + k0);
        float4 w4 = *(const float4*)(Wload + k0);
        __syncthreads();
        As[kv + 0][rA] = a4.x; As[kv + 1][rA] = a4.y;
        As[kv + 2][rA] = a4.z; As[kv + 3][rA] = a4.w;
        Ws[kv + 0][rA] = w4.x; Ws[kv + 1][rA] = w4.y;
        Ws[kv + 2][rA] = w4.z; Ws[kv + 3][rA] = w4.w;
        __syncthreads();
#pragma unroll
        for (int kk = 0; kk < 16; ++kk) {
            float4 av = *(const float4*)(&As[kk][tr << 2]);
            float4 wv = *(const float4*)(&Ws[kk][tc << 2]);
            float aa[4] = {av.x, av.y, av.z, av.w};
            float ww[4] = {wv.x, wv.y, wv.z, wv.w};
#pragma unroll
            for (int i = 0; i < 4; ++i)
#pragma unroll
                for (int j = 0; j < 4; ++j)
                    acc[i][j] = fmaf(aa[i], ww[j], acc[i][j]);
        }
    }

    // Epilogue
    float s[4], tsh[4];
#pragma unroll
    for (int j = 0; j < 4; ++j) {
        int col = n0 + (tc << 2) + j;
        if (EPI == 0 || EPI == 1) {
            float sc = bng[col] * rsqrtf(bnv[col] + BN_EPS);
            s[j]   = sc;
            tsh[j] = bnb[col] - bnm[col] * sc;
        } else {
            s[j]   = 1.f;
            tsh[j] = bias[col];
        }
    }
#pragma unroll
    for (int i = 0; i < 4; ++i) {
        int row = m0 + (tr << 2) + i;
        float v[4];
#pragma unroll
        for (int j = 0; j < 4; ++j) v[j] = acc[i][j] * s[j] + tsh[j];
        if (EPI == 1) {
            float4 r4 = *(const float4*)(res + (size_t)row * ldres + n0 + (tc << 2));
            v[0] += r4.x; v[1] += r4.y; v[2] += r4.z; v[3] += r4.w;
        }
        if (EPI == 0 || EPI == 1) {
#pragma unroll
            for (int j = 0; j < 4; ++j) v[j] = fmaxf(v[j], 0.f);
        }
        float4 o4 = {v[0], v[1], v[2], v[3]};
        *(float4*)(Cout + (size_t)row * ldc + n0 + (tc << 2)) = o4;
    }
}

// ---------------------------------------------------------------------------
// 3x3 conv (dilation DIL), NHWC [B][1024][128] -> out cols [ocol0..ocol0+127]
// of a [B][1024][ldo] buffer. Weights pre-transposed to wt[tap][ic][oc].
// One block per (h,b): stages rows h-DIL, h, h+DIL in LDS (48 KB).
// 256 thr: lane group t&31 -> 4 output channels, t>>5 -> 4 positions.
// ---------------------------------------------------------------------------
template <int DIL>
__global__ __launch_bounds__(256) void conv3x3(
    const float* __restrict__ in, const float* __restrict__ wt,
    const float* __restrict__ bng, const float* __restrict__ bnb,
    const float* __restrict__ bnm, const float* __restrict__ bnv,
    float* __restrict__ outp, int ldo, int ocol0)
{
    __shared__ float lds[3 * 32 * 128];
    const int h = blockIdx.x;   // 0..31
    const int b = blockIdx.y;   // 0..15
    const int t = threadIdx.x;

#pragma unroll
    for (int rr = 0; rr < 3; ++rr) {
        int hr = h + (rr - 1) * DIL;
        float4* dst = (float4*)(lds + rr * 4096);
        if (hr >= 0 && hr < 32) {
            const float4* src = (const float4*)(in + ((size_t)(b * 1024 + hr * 32) << 7));
            for (int i = t; i < 1024; i += 256) dst[i] = src[i];
        } else {
            float4 z = {0.f, 0.f, 0.f, 0.f};
            for (int i = t; i < 1024; i += 256) dst[i] = z;
        }
    }
    __syncthreads();

    const int oc4 = (t & 31) << 2;
    const int q   = t >> 5;  // position group: w = q*4 + p
    float acc[4][4] = {};    // [pos][oc]

#pragma unroll
    for (int dh = -1; dh <= 1; ++dh) {
        int hr = h + dh * DIL;
        if (hr < 0 || hr >= 32) continue;
        const float* lrow = lds + (dh + 1) * 4096;
#pragma unroll
        for (int dw = -1; dw <= 1; ++dw) {
            int tap = (dh + 1) * 3 + (dw + 1);
            const float* wrow = wt + ((size_t)tap << 14);  // tap*128*128
            int  wc[4];
            bool val[4];
#pragma unroll
            for (int p = 0; p < 4; ++p) {
                int wcol = (q << 2) + p + dw * DIL;
                val[p] = (wcol >= 0 && wcol < 32);
                wc[p]  = wcol << 7;
            }
            for (int ic = 0; ic < 128; ++ic) {
                float4 w4 = *(const float4*)(wrow + (ic << 7) + oc4);
#pragma unroll
                for (int p = 0; p < 4; ++p) {
                    float a = val[p] ? lrow[wc[p] + ic] : 0.f;
                    acc[p][0] = fmaf(a, w4.x, acc[p][0]);
                    acc[p][1] = fmaf(a, w4.y, acc[p][1]);
                    acc[p][2] = fmaf(a, w4.z, acc[p][2]);
                    acc[p][3] = fmaf(a, w4.w, acc[p][3]);
                }
            }
        }
    }

    float s[4], tsh[4];
#pragma unroll
    for (int j = 0; j < 4; ++j) {
        int cch = oc4 + j;
        float sc = bng[cch] * rsqrtf(bnv[cch] + BN_EPS);
        s[j]   = sc;
        tsh[j] = bnb[cch] - bnm[cch] * sc;
    }
#pragma unroll
    for (int p = 0; p < 4; ++p) {
        int n = (h << 5) + (q << 2) + p;
        float4 o4;
        o4.x = fmaxf(acc[p][0] * s[0] + tsh[0], 0.f);
        o4.y = fmaxf(acc[p][1] * s[1] + tsh[1], 0.f);
        o4.z = fmaxf(acc[p][2] * s[2] + tsh[2], 0.f);
        o4.w = fmaxf(acc[p][3] * s[3] + tsh[3], 0.f);
        *(float4*)(outp + (size_t)(b * 1024 + n) * ldo + ocol0 + oc4) = o4;
    }
}

// ---------------------------------------------------------------------------
// conv weight transpose: w[oc][ic][tap] -> wt[tap][ic][oc]  (128*128*9)
// ---------------------------------------------------------------------------
__global__ __launch_bounds__(256) void transpose_w(
    const float* __restrict__ w, float* __restrict__ wt)
{
    int i = blockIdx.x * 256 + threadIdx.x;  // 147456 total
    if (i >= 147456) return;
    int oc = i & 127, ic = (i >> 7) & 127, tap = i >> 14;
    wt[i] = w[((oc << 7) + ic) * 9 + tap];
}

// ---------------------------------------------------------------------------
// L2-normalize rows of [16384][512] in place. 1 wave per row, 4 rows/block.
// ---------------------------------------------------------------------------
__global__ __launch_bounds__(256) void l2norm_rows(float* __restrict__ x)
{
    const int t    = threadIdx.x;
    const int wv   = t >> 6, lane = t & 63;
    const int row  = (blockIdx.x << 2) + wv;
    float* p = x + (size_t)row * 512 + (lane << 3);
    float4 a = *(float4*)p;
    float4 b = *(float4*)(p + 4);
    float ss = a.x * a.x + a.y * a.y + a.z * a.z + a.w * a.w +
               b.x * b.x + b.y * b.y + b.z * b.z + b.w * b.w;
#pragma unroll
    for (int off = 32; off >= 1; off >>= 1) ss += __shfl_xor(ss, off);
    float sc = 1.f / fmaxf(sqrtf(ss), 1e-12f);
    a.x *= sc; a.y *= sc; a.z *= sc; a.w *= sc;
    b.x *= sc; b.y *= sc; b.z *= sc; b.w *= sc;
    *(float4*)p       = a;
    *(float4*)(p + 4) = b;
}

// ---------------------------------------------------------------------------
// sims + max over protos: per block, 64 rows of xn x 64 protos of class c,
// K=512. Epilogue: per-row max over the 64 protos -> act[b][c][n].
// ---------------------------------------------------------------------------
__global__ __launch_bounds__(256) void sims_max(
    const float* __restrict__ xn, const float* __restrict__ protos,
    float* __restrict__ act)
{
    __shared__ float As[16][64];
    __shared__ float Ws[16][64];
    __shared__ float red[64][17];
    const int t  = threadIdx.x;
    const int tr = t >> 4, tc = t & 15;
    const int rA = t >> 2, kv = (t & 3) << 2;
    const int m0 = blockIdx.x << 6;
    const int c  = blockIdx.y;

    const float* Aload = xn + (size_t)(m0 + rA) * 512 + kv;
    const float* Wload = protos + ((size_t)c * 64 + rA) * 512 + kv;

    float acc[4][4] = {};
    for (int k0 = 0; k0 < 512; k0 += 16) {
        float4 a4 = *(const float4*)(Aload + k0);
        float4 w4 = *(const float4*)(Wload + k0);
        __syncthreads();
        As[kv + 0][rA] = a4.x; As[kv + 1][rA] = a4.y;
        As[kv + 2][rA] = a4.z; As[kv + 3][rA] = a4.w;
        Ws[kv + 0][rA] = w4.x; Ws[kv + 1][rA] = w4.y;
        Ws[kv + 2][rA] = w4.z; Ws[kv + 3][rA] = w4.w;
        __syncthreads();
#pragma unroll
        for (int kk = 0; kk < 16; ++kk) {
            float4 av = *(const float4*)(&As[kk][tr << 2]);
            float4 wv = *(const float4*)(&Ws[kk][tc << 2]);
            float aa[4] = {av.x, av.y, av.z, av.w};
            float ww[4] = {wv.x, wv.y, wv.z, wv.w};
#pragma unroll
            for (int i = 0; i < 4; ++i)
#pragma unroll
                for (int j = 0; j < 4; ++j)
                    acc[i][j] = fmaf(aa[i], ww[j], acc[i][j]);
        }
    }

#pragma unroll
    for (int i = 0; i < 4; ++i) {
        float mx = fmaxf(fmaxf(acc[i][0], acc[i][1]), fmaxf(acc[i][2], acc[i][3]));
        red[(tr << 2) + i][tc] = mx;
    }
    __syncthreads();
    if (t < 64) {
        float mx = red[t][0];
#pragma unroll
        for (int j = 1; j < 16; ++j) mx = fmaxf(mx, red[t][j]);
        int m = m0 + t;
        int b = m >> 10, n = m & 1023;
        act[(((size_t)(b * 20 + c)) << 10) + n] = mx;
    }
}

// ---------------------------------------------------------------------------
// logits: per (b,c) max over n of act, times logit_scale.
// ---------------------------------------------------------------------------
__global__ __launch_bounds__(256) void logits_max(
    const float* __restrict__ act, const float* __restrict__ lsc,
    float* __restrict__ logits)
{
    const int bc = blockIdx.x;  // 0..319
    const int t  = threadIdx.x;
    float4 v = *(const float4*)(act + ((size_t)bc << 10) + (t << 2));
    float mx = fmaxf(fmaxf(v.x, v.y), fmaxf(v.z, v.w));
#pragma unroll
    for (int off = 32; off >= 1; off >>= 1) mx = fmaxf(mx, __shfl_xor(mx, off));
    __shared__ float wm[4];
    if ((t & 63) == 0) wm[t >> 6] = mx;
    __syncthreads();
    if (t == 0) {
        float m2 = fmaxf(fmaxf(wm[0], wm[1]), fmaxf(wm[2], wm[3]));
        logits[bc] = m2 * lsc[0];
    }
}

// ---------------------------------------------------------------------------
extern "C" void kernel_launch(void* const* d_in, const int* in_sizes, int n_in,
                              void* d_out, int out_size, void* d_ws, size_t ws_size,
                              hipStream_t stream)
{
    const float* pf   = (const float*)d_in[0];
    const float* prot = (const float*)d_in[1];
    const float* w0   = (const float*)d_in[2];
    const float* g0   = (const float*)d_in[3];
    const float* b0   = (const float*)d_in[4];
    const float* m0v  = (const float*)d_in[5];
    const float* v0   = (const float*)d_in[6];
    const float* wr   = (const float*)d_in[7];
    const float* gr   = (const float*)d_in[8];
    const float* br   = (const float*)d_in[9];
    const float* mr   = (const float*)d_in[10];
    const float* vr   = (const float*)d_in[11];
    const float* wl   = (const float*)d_in[12];
    const float* gl   = (const float*)d_in[13];
    const float* bl   = (const float*)d_in[14];
    const float* ml   = (const float*)d_in[15];
    const float* vl   = (const float*)d_in[16];
    const float* wg   = (const float*)d_in[17];
    const float* gG   = (const float*)d_in[18];
    const float* bG   = (const float*)d_in[19];
    const float* mG   = (const float*)d_in[20];
    const float* vG   = (const float*)d_in[21];
    const float* wp   = (const float*)d_in[22];
    const float* gp   = (const float*)d_in[23];
    const float* bp   = (const float*)d_in[24];
    const float* mp   = (const float*)d_in[25];
    const float* vp   = (const float*)d_in[26];
    const float* wf   = (const float*)d_in[27];
    const float* bf   = (const float*)d_in[28];
    const float* lsc  = (const float*)d_in[29];

    float* ws  = (float*)d_ws;
    float* x1  = ws;               // [16384][512]
    float* o   = ws + 8388608;     // [16384][128]
    float* lg  = ws + 10485760;    // [16384][256]  (l: 0..127, g: 128..255)
    float* x2  = ws + 14680064;    // [16384][512]
    float* wtl = ws + 23068672;    // [9][128][128]
    float* wtg = ws + 23216128;    // [9][128][128]

    float* out    = (float*)d_out;
    float* logits = out;            // [16][20]
    float* act    = out + 320;      // [16][20][1024]
    float* xo     = out + 328000;   // [16384][512]

    // conv weight transposes
    transpose_w<<<576, 256, 0, stream>>>(wl, wtl);
    transpose_w<<<576, 256, 0, stream>>>(wg, wtg);

    // adapter: pf[16384][768] x w0[512][768]^T -> BN -> ReLU -> x1
    gemm_nt<0><<<dim3(256, 8), 256, 0, stream>>>(
        pf, 768, w0, 768, x1, 512, 768, g0, b0, m0v, v0, nullptr, 0, nullptr);

    // reduce: x1 x wr[128][512]^T -> BN -> ReLU -> o
    gemm_nt<0><<<dim3(256, 2), 256, 0, stream>>>(
        x1, 512, wr, 512, o, 128, 512, gr, br, mr, vr, nullptr, 0, nullptr);

    // local 3x3 (dil=1) and global 3x3 (dil=2) branches -> lg
    conv3x3<1><<<dim3(32, 16), 256, 0, stream>>>(o, wtl, gl, bl, ml, vl, lg, 256, 0);
    conv3x3<2><<<dim3(32, 16), 256, 0, stream>>>(o, wtg, gG, bG, mG, vG, lg, 256, 128);

    // project: lg[16384][256] x wp[512][256]^T -> BN -> +x1 -> ReLU -> x2
    gemm_nt<1><<<dim3(256, 8), 256, 0, stream>>>(
        lg, 256, wp, 256, x2, 512, 256, gp, bp, mp, vp, x1, 512, nullptr);

    // final: x2 x wf[512][512]^T + bf -> xo (in d_out)
    gemm_nt<2><<<dim3(256, 8), 256, 0, stream>>>(
        x2, 512, wf, 512, xo, 512, 512, nullptr, nullptr, nullptr, nullptr,
        nullptr, 0, bf);

    // L2 normalize rows of xo in place
    l2norm_rows<<<4096, 256, 0, stream>>>(xo);

    // sims + max over protos -> act_maps
    sims_max<<<dim3(256, 20), 256, 0, stream>>>(xo, prot, act);

    // logits = max over n * logit_scale
    logits_max<<<320, 256, 0, stream>>>(act, lsc, logits);
}

// Round 2
// 226.892 us; speedup vs baseline: 4.8132x; 4.8132x over previous
//
#include <hip/hip_runtime.h>
#include <math.h>

#define BN_EPS 1e-5f

typedef __attribute__((ext_vector_type(8))) short short8v;   // 8 x bf16 bits
typedef __attribute__((ext_vector_type(8))) unsigned short ushort8v;
typedef __attribute__((ext_vector_type(4))) float f32x4;

// fp32 -> bf16 (RNE)
__device__ __forceinline__ unsigned short f2b(float f) {
    unsigned int u = __float_as_uint(f);
    return (unsigned short)((u + 0x7FFFu + ((u >> 16) & 1u)) >> 16);
}
__device__ __forceinline__ float b2f(unsigned short h) {
    return __uint_as_float(((unsigned int)h) << 16);
}

// ---------------------------------------------------------------------------
// fp32 -> bf16 convert, 8 elems/thread. n8 = n/8.
// ---------------------------------------------------------------------------
__global__ __launch_bounds__(256) void f2b_kernel(
    const float* __restrict__ in, unsigned short* __restrict__ out, int n8)
{
    int i = blockIdx.x * 256 + threadIdx.x;
    if (i >= n8) return;
    const float4* p = (const float4*)(in + (size_t)i * 8);
    float4 a = p[0], b = p[1];
    ushort8v r;
    r[0] = f2b(a.x); r[1] = f2b(a.y); r[2] = f2b(a.z); r[3] = f2b(a.w);
    r[4] = f2b(b.x); r[5] = f2b(b.y); r[6] = f2b(b.z); r[7] = f2b(b.w);
    *(ushort8v*)(out + (size_t)i * 8) = r;
}

// conv weights: w[oc][ic][3][3] fp32 -> wt[branch][tap][oc][ic] bf16
__global__ __launch_bounds__(256) void convw_kernel(
    const float* __restrict__ wl, const float* __restrict__ wg,
    unsigned short* __restrict__ out)
{
    int i = blockIdx.x * 256 + threadIdx.x;
    if (i >= 294912) return;
    int br = i >= 147456;
    int j  = i - br * 147456;
    int tap = j >> 14, oc = (j >> 7) & 127, ic = j & 127;
    const float* src = br ? wg : wl;
    out[i] = f2b(src[((oc << 7) + ic) * 9 + tap]);
}

// zero a bf16 buffer, 8 elems/thread
__global__ __launch_bounds__(256) void zero_kernel(unsigned short* __restrict__ p, int n8)
{
    int i = blockIdx.x * 256 + threadIdx.x;
    if (i >= n8) return;
    ushort8v z;
#pragma unroll
    for (int k = 0; k < 8; ++k) z[k] = 0;
    *(ushort8v*)(p + (size_t)i * 8) = z;
}

// ---------------------------------------------------------------------------
// bf16 MFMA NT GEMM: C[M][Nc] = A[M][K] * W[Nc][K]^T
// Tile 128x128, BK=32, 256 threads (4 waves, 2x2), 4x4 fragments/wave.
// LDS layout fragment-major: [kb 0..3][row 0..127] of short8 (8 k-elems).
// EPI 0: BN+ReLU -> bf16    EPI 1: BN+res+ReLU -> bf16
// EPI 2: +bias -> fp32      EPI 3: BN+ReLU -> bf16 at padded conv layout
// ---------------------------------------------------------------------------
template <int EPI>
__global__ __launch_bounds__(256) void mfma_gemm(
    const unsigned short* __restrict__ A, int lda,
    const unsigned short* __restrict__ Wt, int ldw,
    void* __restrict__ outp, int ldc, int Kdim,
    const float* __restrict__ bng, const float* __restrict__ bnb,
    const float* __restrict__ bnm, const float* __restrict__ bnv,
    const unsigned short* __restrict__ res, int ldres,
    const float* __restrict__ bias)
{
    __shared__ short8v Asta[512];
    __shared__ short8v Bsta[512];
    const int t  = threadIdx.x;
    const int l  = t & 63, w = t >> 6;
    const int wm = w >> 1, wn = w & 1;
    const int m0 = blockIdx.x << 7, n0 = blockIdx.y << 7;

    const int r0  = t & 127;       // staged row (chunk t and t+256 share it)
    const int kb0 = t >> 7;        // k-block 0/1; second chunk is kb0+2

    const unsigned short* Ap = A  + (size_t)(m0 + r0) * lda + kb0 * 8;
    const unsigned short* Bp = Wt + (size_t)(n0 + r0) * ldw + kb0 * 8;

    f32x4 acc[4][4];
#pragma unroll
    for (int mf = 0; mf < 4; ++mf)
#pragma unroll
        for (int nf = 0; nf < 4; ++nf)
#pragma unroll
            for (int j = 0; j < 4; ++j) acc[mf][nf][j] = 0.f;

    const int arow = wm * 64 + (l & 15);
    const int brow = wn * 64 + (l & 15);
    const int kq   = l >> 4;

    for (int k0 = 0; k0 < Kdim; k0 += 32) {
        short8v a0 = *(const short8v*)(Ap + k0);
        short8v a1 = *(const short8v*)(Ap + k0 + 16);
        short8v b0 = *(const short8v*)(Bp + k0);
        short8v b1 = *(const short8v*)(Bp + k0 + 16);
        __syncthreads();
        Asta[kb0 * 128 + r0]       = a0;
        Asta[(kb0 + 2) * 128 + r0] = a1;
        Bsta[kb0 * 128 + r0]       = b0;
        Bsta[(kb0 + 2) * 128 + r0] = b1;
        __syncthreads();
        short8v af[4], bfv[4];
#pragma unroll
        for (int mf = 0; mf < 4; ++mf) af[mf]  = Asta[kq * 128 + arow + mf * 16];
#pragma unroll
        for (int nf = 0; nf < 4; ++nf) bfv[nf] = Bsta[kq * 128 + brow + nf * 16];
#pragma unroll
        for (int mf = 0; mf < 4; ++mf)
#pragma unroll
            for (int nf = 0; nf < 4; ++nf)
                acc[mf][nf] = __builtin_amdgcn_mfma_f32_16x16x32_bf16(
                    af[mf], bfv[nf], acc[mf][nf], 0, 0, 0);
    }

    // Epilogue
    float s[4], sh[4];
    int cols[4];
#pragma unroll
    for (int nf = 0; nf < 4; ++nf) {
        int col = n0 + wn * 64 + nf * 16 + (l & 15);
        cols[nf] = col;
        if (EPI == 2) { s[nf] = 1.f; sh[nf] = bias[col]; }
        else {
            float sc = bng[col] * rsqrtf(bnv[col] + BN_EPS);
            s[nf]  = sc;
            sh[nf] = bnb[col] - bnm[col] * sc;
        }
    }
#pragma unroll
    for (int mf = 0; mf < 4; ++mf) {
#pragma unroll
        for (int j = 0; j < 4; ++j) {
            int row = m0 + wm * 64 + mf * 16 + kq * 4 + j;
#pragma unroll
            for (int nf = 0; nf < 4; ++nf) {
                float v = acc[mf][nf][j] * s[nf] + sh[nf];
                if (EPI == 1) v += b2f(res[(size_t)row * ldres + cols[nf]]);
                if (EPI != 2) v = fmaxf(v, 0.f);
                if (EPI == 2) {
                    ((float*)outp)[(size_t)row * ldc + cols[nf]] = v;
                } else if (EPI == 3) {
                    int b = row >> 10, h = (row >> 5) & 31, ww = row & 31;
                    size_t pidx = ((size_t)(b * 36 + h + 2) * 36 + (ww + 2)) * 128 + cols[nf];
                    ((unsigned short*)outp)[pidx] = f2b(v);
                } else {
                    ((unsigned short*)outp)[(size_t)row * ldc + cols[nf]] = f2b(v);
                }
            }
        }
    }
}

// ---------------------------------------------------------------------------
// Both 3x3 convs as 9 accumulated per-tap MFMA GEMMs over padded input.
// opad: [16][36][36][128] bf16 (pad=2, zeroed). blockIdx.y: 0=local(dil1),
// 1=global(dil2). Tile 128 rows x 128 oc. Output: lg[m][br*128 + oc] bf16.
// ---------------------------------------------------------------------------
__global__ __launch_bounds__(256) void conv_mfma(
    const unsigned short* __restrict__ opad,
    const unsigned short* __restrict__ wt_all,
    const float* __restrict__ g1, const float* __restrict__ b1,
    const float* __restrict__ m1, const float* __restrict__ v1,
    const float* __restrict__ g2, const float* __restrict__ b2,
    const float* __restrict__ m2, const float* __restrict__ v2,
    unsigned short* __restrict__ lg)
{
    __shared__ short8v Asta[512];
    __shared__ short8v Bsta[512];
    const int t  = threadIdx.x;
    const int l  = t & 63, w = t >> 6;
    const int wm = w >> 1, wn = w & 1;
    const int m0 = blockIdx.x << 7;
    const int br = blockIdx.y;
    const int dil = 1 + br;
    const unsigned short* wtb = wt_all + (size_t)br * 147456;

    const int r0  = t & 127;
    const int kb0 = t >> 7;
    const int m   = m0 + r0;
    const int bb  = m >> 10, h = (m >> 5) & 31, wc = m & 31;
    const ptrdiff_t pbase = ((ptrdiff_t)(bb * 36 + h + 2) * 36 + (wc + 2)) * 128;

    f32x4 acc[4][4];
#pragma unroll
    for (int mf = 0; mf < 4; ++mf)
#pragma unroll
        for (int nf = 0; nf < 4; ++nf)
#pragma unroll
            for (int j = 0; j < 4; ++j) acc[mf][nf][j] = 0.f;

    const int arow = wm * 64 + (l & 15);
    const int brow = wn * 64 + (l & 15);
    const int kq   = l >> 4;

    for (int tap = 0; tap < 9; ++tap) {
        const int dh = tap / 3 - 1, dw = tap % 3 - 1;
        const unsigned short* Ap  = opad + pbase + (ptrdiff_t)((dh * 36 + dw) * dil) * 128 + kb0 * 8;
        const unsigned short* Bpt = wtb + (size_t)tap * 16384 + (size_t)r0 * 128 + kb0 * 8;
#pragma unroll
        for (int k0 = 0; k0 < 128; k0 += 32) {
            short8v a0 = *(const short8v*)(Ap + k0);
            short8v a1 = *(const short8v*)(Ap + k0 + 16);
            short8v b0 = *(const short8v*)(Bpt + k0);
            short8v b1 = *(const short8v*)(Bpt + k0 + 16);
            __syncthreads();
            Asta[kb0 * 128 + r0]       = a0;
            Asta[(kb0 + 2) * 128 + r0] = a1;
            Bsta[kb0 * 128 + r0]       = b0;
            Bsta[(kb0 + 2) * 128 + r0] = b1;
            __syncthreads();
            short8v af[4], bfv[4];
#pragma unroll
            for (int mf = 0; mf < 4; ++mf) af[mf]  = Asta[kq * 128 + arow + mf * 16];
#pragma unroll
            for (int nf = 0; nf < 4; ++nf) bfv[nf] = Bsta[kq * 128 + brow + nf * 16];
#pragma unroll
            for (int mf = 0; mf < 4; ++mf)
#pragma unroll
                for (int nf = 0; nf < 4; ++nf)
                    acc[mf][nf] = __builtin_amdgcn_mfma_f32_16x16x32_bf16(
                        af[mf], bfv[nf], acc[mf][nf], 0, 0, 0);
        }
    }

    const float* gg = br ? g2 : g1;
    const float* gb = br ? b2 : b1;
    const float* gm = br ? m2 : m1;
    const float* gv = br ? v2 : v1;
    float s[4], sh[4];
    int cols[4];
#pragma unroll
    for (int nf = 0; nf < 4; ++nf) {
        int col = wn * 64 + nf * 16 + (l & 15);
        cols[nf] = col;
        float sc = gg[col] * rsqrtf(gv[col] + BN_EPS);
        s[nf]  = sc;
        sh[nf] = gb[col] - gm[col] * sc;
    }
#pragma unroll
    for (int mf = 0; mf < 4; ++mf) {
#pragma unroll
        for (int j = 0; j < 4; ++j) {
            int row = m0 + wm * 64 + mf * 16 + kq * 4 + j;
#pragma unroll
            for (int nf = 0; nf < 4; ++nf) {
                float v = fmaxf(acc[mf][nf][j] * s[nf] + sh[nf], 0.f);
                lg[(size_t)row * 256 + br * 128 + cols[nf]] = f2b(v);
            }
        }
    }
}

// ---------------------------------------------------------------------------
// L2-normalize rows of fp32 [16384][512] in place; also write bf16 copy.
// ---------------------------------------------------------------------------
__global__ __launch_bounds__(256) void l2norm_rows(
    float* __restrict__ x, unsigned short* __restrict__ xn)
{
    const int t    = threadIdx.x;
    const int wv   = t >> 6, lane = t & 63;
    const int row  = (blockIdx.x << 2) + wv;
    float* p = x + (size_t)row * 512 + (lane << 3);
    float4 a = *(float4*)p;
    float4 b = *(float4*)(p + 4);
    float ss = a.x * a.x + a.y * a.y + a.z * a.z + a.w * a.w +
               b.x * b.x + b.y * b.y + b.z * b.z + b.w * b.w;
#pragma unroll
    for (int off = 32; off >= 1; off >>= 1) ss += __shfl_xor(ss, off);
    float sc = 1.f / fmaxf(sqrtf(ss), 1e-12f);
    a.x *= sc; a.y *= sc; a.z *= sc; a.w *= sc;
    b.x *= sc; b.y *= sc; b.z *= sc; b.w *= sc;
    *(float4*)p       = a;
    *(float4*)(p + 4) = b;
    ushort8v r;
    r[0] = f2b(a.x); r[1] = f2b(a.y); r[2] = f2b(a.z); r[3] = f2b(a.w);
    r[4] = f2b(b.x); r[5] = f2b(b.y); r[6] = f2b(b.z); r[7] = f2b(b.w);
    *(ushort8v*)(xn + (size_t)row * 512 + (lane << 3)) = r;
}

// ---------------------------------------------------------------------------
// sims + max over 64 protos of one class. Tile 128 rows x 64 protos, K=512.
// 4 waves: wave w rows w*32..w*32+31 (2 M-frags), all 64 proto cols (4 N-frags).
// Epilogue: in-register max over nf + shfl_xor over the 16-col lane group.
// ---------------------------------------------------------------------------
__global__ __launch_bounds__(256) void sims_mfma(
    const unsigned short* __restrict__ xn,
    const unsigned short* __restrict__ protos,
    float* __restrict__ act)
{
    __shared__ short8v Asta[512];
    __shared__ short8v Bsta[256];
    const int t = threadIdx.x;
    const int l = t & 63, w = t >> 6;
    const int m0 = blockIdx.x << 7;
    const int c  = blockIdx.y;

    const int r0  = t & 127, kb0 = t >> 7;   // A chunks (2/thread)
    const int rb  = t & 63,  kbb = t >> 6;   // B chunks (1/thread)
    const unsigned short* Ap = xn + (size_t)(m0 + r0) * 512 + kb0 * 8;
    const unsigned short* Bp = protos + ((size_t)c * 64 + rb) * 512 + kbb * 8;

    f32x4 acc[2][4];
#pragma unroll
    for (int mf = 0; mf < 2; ++mf)
#pragma unroll
        for (int nf = 0; nf < 4; ++nf)
#pragma unroll
            for (int j = 0; j < 4; ++j) acc[mf][nf][j] = 0.f;

    const int arow = w * 32 + (l & 15);
    const int brow = l & 15;
    const int kq   = l >> 4;

    for (int k0 = 0; k0 < 512; k0 += 32) {
        short8v a0 = *(const short8v*)(Ap + k0);
        short8v a1 = *(const short8v*)(Ap + k0 + 16);
        short8v b0 = *(const short8v*)(Bp + k0);
        __syncthreads();
        Asta[kb0 * 128 + r0]       = a0;
        Asta[(kb0 + 2) * 128 + r0] = a1;
        Bsta[kbb * 64 + rb]        = b0;
        __syncthreads();
        short8v af[2], bfv[4];
        af[0] = Asta[kq * 128 + arow];
        af[1] = Asta[kq * 128 + arow + 16];
#pragma unroll
        for (int nf = 0; nf < 4; ++nf) bfv[nf] = Bsta[kq * 64 + brow + nf * 16];
#pragma unroll
        for (int mf = 0; mf < 2; ++mf)
#pragma unroll
            for (int nf = 0; nf < 4; ++nf)
                acc[mf][nf] = __builtin_amdgcn_mfma_f32_16x16x32_bf16(
                    af[mf], bfv[nf], acc[mf][nf], 0, 0, 0);
    }

#pragma unroll
    for (int mf = 0; mf < 2; ++mf) {
        float vj[4];
#pragma unroll
        for (int j = 0; j < 4; ++j) {
            float v = fmaxf(fmaxf(acc[mf][0][j], acc[mf][1][j]),
                            fmaxf(acc[mf][2][j], acc[mf][3][j]));
            v = fmaxf(v, __shfl_xor(v, 1));
            v = fmaxf(v, __shfl_xor(v, 2));
            v = fmaxf(v, __shfl_xor(v, 4));
            v = fmaxf(v, __shfl_xor(v, 8));
            vj[j] = v;
        }
        if ((l & 15) == 0) {
            int rowb = m0 + w * 32 + mf * 16 + kq * 4;
#pragma unroll
            for (int j = 0; j < 4; ++j) {
                int row = rowb + j;
                int bb = row >> 10, n = row & 1023;
                act[(((size_t)(bb * 20 + c)) << 10) + n] = vj[j];
            }
        }
    }
}

// ---------------------------------------------------------------------------
// logits: per (b,c) max over n of act, times logit_scale.
// ---------------------------------------------------------------------------
__global__ __launch_bounds__(256) void logits_max(
    const float* __restrict__ act, const float* __restrict__ lsc,
    float* __restrict__ logits)
{
    const int bc = blockIdx.x;
    const int t  = threadIdx.x;
    float4 v = *(const float4*)(act + ((size_t)bc << 10) + (t << 2));
    float mx = fmaxf(fmaxf(v.x, v.y), fmaxf(v.z, v.w));
#pragma unroll
    for (int off = 32; off >= 1; off >>= 1) mx = fmaxf(mx, __shfl_xor(mx, off));
    __shared__ float wm[4];
    if ((t & 63) == 0) wm[t >> 6] = mx;
    __syncthreads();
    if (t == 0) {
        float m2 = fmaxf(fmaxf(wm[0], wm[1]), fmaxf(wm[2], wm[3]));
        logits[bc] = m2 * lsc[0];
    }
}

// ---------------------------------------------------------------------------
extern "C" void kernel_launch(void* const* d_in, const int* in_sizes, int n_in,
                              void* d_out, int out_size, void* d_ws, size_t ws_size,
                              hipStream_t stream)
{
    const float* pf   = (const float*)d_in[0];
    const float* prot = (const float*)d_in[1];
    const float* w0   = (const float*)d_in[2];
    const float* g0   = (const float*)d_in[3];
    const float* b0   = (const float*)d_in[4];
    const float* m0v  = (const float*)d_in[5];
    const float* v0   = (const float*)d_in[6];
    const float* wr   = (const float*)d_in[7];
    const float* gr   = (const float*)d_in[8];
    const float* br   = (const float*)d_in[9];
    const float* mr   = (const float*)d_in[10];
    const float* vr   = (const float*)d_in[11];
    const float* wl   = (const float*)d_in[12];
    const float* gl   = (const float*)d_in[13];
    const float* bl   = (const float*)d_in[14];
    const float* ml   = (const float*)d_in[15];
    const float* vl   = (const float*)d_in[16];
    const float* wg   = (const float*)d_in[17];
    const float* gG   = (const float*)d_in[18];
    const float* bG   = (const float*)d_in[19];
    const float* mG   = (const float*)d_in[20];
    const float* vG   = (const float*)d_in[21];
    const float* wp   = (const float*)d_in[22];
    const float* gp   = (const float*)d_in[23];
    const float* bp   = (const float*)d_in[24];
    const float* mp   = (const float*)d_in[25];
    const float* vp   = (const float*)d_in[26];
    const float* wf   = (const float*)d_in[27];
    const float* bf_  = (const float*)d_in[28];
    const float* lsc  = (const float*)d_in[29];

    char* ws = (char*)d_ws;
    unsigned short* pf_bf    = (unsigned short*)(ws);             // 25165824 B
    unsigned short* w0_bf    = (unsigned short*)(ws + 25165824);  // 786432
    unsigned short* wr_bf    = (unsigned short*)(ws + 25952256);  // 131072
    unsigned short* wt_bf    = (unsigned short*)(ws + 26083328);  // 589824
    unsigned short* wp_bf    = (unsigned short*)(ws + 26673152);  // 262144
    unsigned short* wf_bf    = (unsigned short*)(ws + 26935296);  // 524288
    unsigned short* prot_bf  = (unsigned short*)(ws + 27459584);  // 1310720
    unsigned short* x1_bf    = (unsigned short*)(ws + 28770304);  // 16777216
    unsigned short* opad     = (unsigned short*)(ws + 45547520);  // 5308416
    unsigned short* lg_bf    = (unsigned short*)(ws + 50855936);  // 8388608
    unsigned short* x2_bf    = (unsigned short*)(ws + 59244544);  // 16777216
    unsigned short* xn_bf    = (unsigned short*)(ws + 76021760);  // 16777216

    float* out    = (float*)d_out;
    float* logits = out;            // [16][20]
    float* act    = out + 320;      // [16][20][1024]
    float* xo     = out + 328000;   // [16384][512] fp32

    // ---- conversions ----
    f2b_kernel<<<6144, 256, 0, stream>>>(pf,   pf_bf,   1572864);
    f2b_kernel<<<192,  256, 0, stream>>>(w0,   w0_bf,   49152);
    f2b_kernel<<<32,   256, 0, stream>>>(wr,   wr_bf,   8192);
    f2b_kernel<<<64,   256, 0, stream>>>(wp,   wp_bf,   16384);
    f2b_kernel<<<128,  256, 0, stream>>>(wf,   wf_bf,   32768);
    f2b_kernel<<<320,  256, 0, stream>>>(prot, prot_bf, 81920);
    convw_kernel<<<1152, 256, 0, stream>>>(wl, wg, wt_bf);
    zero_kernel<<<1296, 256, 0, stream>>>(opad, 331776);

    // ---- adapter: pf x w0^T -> BN -> ReLU -> x1 (bf16) ----
    mfma_gemm<0><<<dim3(128, 4), 256, 0, stream>>>(
        pf_bf, 768, w0_bf, 768, x1_bf, 512, 768,
        g0, b0, m0v, v0, nullptr, 0, nullptr);

    // ---- reduce: x1 x wr^T -> BN -> ReLU -> opad (padded bf16) ----
    mfma_gemm<3><<<dim3(128, 1), 256, 0, stream>>>(
        x1_bf, 512, wr_bf, 512, opad, 0, 512,
        gr, br, mr, vr, nullptr, 0, nullptr);

    // ---- both 3x3 conv branches -> lg (bf16 [16384][256]) ----
    conv_mfma<<<dim3(128, 2), 256, 0, stream>>>(
        opad, wt_bf, gl, bl, ml, vl, gG, bG, mG, vG, lg_bf);

    // ---- project: lg x wp^T -> BN -> +x1 -> ReLU -> x2 (bf16) ----
    mfma_gemm<1><<<dim3(128, 4), 256, 0, stream>>>(
        lg_bf, 256, wp_bf, 256, x2_bf, 512, 256,
        gp, bp, mp, vp, x1_bf, 512, nullptr);

    // ---- final: x2 x wf^T + bf -> xo (fp32 in d_out) ----
    mfma_gemm<2><<<dim3(128, 4), 256, 0, stream>>>(
        x2_bf, 512, wf_bf, 512, xo, 512, 512,
        nullptr, nullptr, nullptr, nullptr, nullptr, 0, bf_);

    // ---- L2 normalize (fp32 in place) + bf16 copy ----
    l2norm_rows<<<4096, 256, 0, stream>>>(xo, xn_bf);

    // ---- sims + max over protos -> act ----
    sims_mfma<<<dim3(128, 20), 256, 0, stream>>>(xn_bf, prot_bf, act);

    // ---- logits ----
    logits_max<<<320, 256, 0, stream>>>(act, lsc, logits);
}

// Round 3
// 204.090 us; speedup vs baseline: 5.3509x; 1.1117x over previous
//
#include <hip/hip_runtime.h>
#include <math.h>

#define BN_EPS 1e-5f

typedef __attribute__((ext_vector_type(8))) short short8v;   // 8 x bf16 bits
typedef __attribute__((ext_vector_type(8))) unsigned short ushort8v;
typedef __attribute__((ext_vector_type(4))) float f32x4;

__device__ __forceinline__ unsigned short f2b(float f) {
    unsigned int u = __float_as_uint(f);
    return (unsigned short)((u + 0x7FFFu + ((u >> 16) & 1u)) >> 16);
}
__device__ __forceinline__ float b2f(unsigned short h) {
    return __uint_as_float(((unsigned int)h) << 16);
}

// ---------------------------------------------------------------------------
// fp32 -> bf16 convert, 8 elems/thread. n8 = n/8.
// ---------------------------------------------------------------------------
__global__ __launch_bounds__(256) void f2b_kernel(
    const float* __restrict__ in, unsigned short* __restrict__ out, int n8)
{
    int i = blockIdx.x * 256 + threadIdx.x;
    if (i >= n8) return;
    const float4* p = (const float4*)(in + (size_t)i * 8);
    float4 a = p[0], b = p[1];
    ushort8v r;
    r[0] = f2b(a.x); r[1] = f2b(a.y); r[2] = f2b(a.z); r[3] = f2b(a.w);
    r[4] = f2b(b.x); r[5] = f2b(b.y); r[6] = f2b(b.z); r[7] = f2b(b.w);
    *(ushort8v*)(out + (size_t)i * 8) = r;
}

// Fused conversion of all small weights (w0, wr, wp, wf, protos), 8/thread.
__global__ __launch_bounds__(256) void f2b_multi(
    const float* __restrict__ w0, const float* __restrict__ wr,
    const float* __restrict__ wp, const float* __restrict__ wf,
    const float* __restrict__ prot,
    unsigned short* __restrict__ w0o, unsigned short* __restrict__ wro,
    unsigned short* __restrict__ wpo, unsigned short* __restrict__ wfo,
    unsigned short* __restrict__ proto)
{
    int i = blockIdx.x * 256 + threadIdx.x;  // 188416 chunks total
    const float* src; unsigned short* dst; int off;
    if      (i <  49152) { src = w0;   dst = w0o;   off = i; }
    else if (i <  57344) { src = wr;   dst = wro;   off = i - 49152; }
    else if (i <  73728) { src = wp;   dst = wpo;   off = i - 57344; }
    else if (i < 106496) { src = wf;   dst = wfo;   off = i - 73728; }
    else if (i < 188416) { src = prot; dst = proto; off = i - 106496; }
    else return;
    const float4* p = (const float4*)(src + (size_t)off * 8);
    float4 a = p[0], b = p[1];
    ushort8v r;
    r[0] = f2b(a.x); r[1] = f2b(a.y); r[2] = f2b(a.z); r[3] = f2b(a.w);
    r[4] = f2b(b.x); r[5] = f2b(b.y); r[6] = f2b(b.z); r[7] = f2b(b.w);
    *(ushort8v*)(dst + (size_t)off * 8) = r;
}

// conv weights: w[oc][ic][3][3] fp32 -> wt[branch][tap][oc][ic] bf16
__global__ __launch_bounds__(256) void convw_kernel(
    const float* __restrict__ wl, const float* __restrict__ wg,
    unsigned short* __restrict__ out)
{
    int i = blockIdx.x * 256 + threadIdx.x;
    if (i >= 294912) return;
    int br = i >= 147456;
    int j  = i - br * 147456;
    int tap = j >> 14, oc = (j >> 7) & 127, ic = j & 127;
    const float* src = br ? wg : wl;
    out[i] = f2b(src[((oc << 7) + ic) * 9 + tap]);
}

__global__ __launch_bounds__(256) void zero_kernel(unsigned short* __restrict__ p, int n8)
{
    int i = blockIdx.x * 256 + threadIdx.x;
    if (i >= n8) return;
    ushort8v z;
#pragma unroll
    for (int k = 0; k < 8; ++k) z[k] = 0;
    *(ushort8v*)(p + (size_t)i * 8) = z;
}

// ---------------------------------------------------------------------------
// bf16 MFMA NT GEMM: C[M][Nc] = A[M][K] * W[Nc][K]^T
// Tile 128x128, BK=32, 256 threads (4 waves, 2x2), 4x4 fragments/wave.
// EPI 0: BN+ReLU->bf16  1: BN+res+ReLU->bf16  2: +bias->fp32  3: BN+ReLU->padded
// ---------------------------------------------------------------------------
template <int EPI>
__global__ __launch_bounds__(256) void mfma_gemm(
    const unsigned short* __restrict__ A, int lda,
    const unsigned short* __restrict__ Wt, int ldw,
    void* __restrict__ outp, int ldc, int Kdim,
    const float* __restrict__ bng, const float* __restrict__ bnb,
    const float* __restrict__ bnm, const float* __restrict__ bnv,
    const unsigned short* __restrict__ res, int ldres,
    const float* __restrict__ bias)
{
    __shared__ short8v Asta[512];
    __shared__ short8v Bsta[512];
    const int t  = threadIdx.x;
    const int l  = t & 63, w = t >> 6;
    const int wm = w >> 1, wn = w & 1;
    const int m0 = blockIdx.x << 7, n0 = blockIdx.y << 7;

    const int r0  = t & 127;
    const int kb0 = t >> 7;

    const unsigned short* Ap = A  + (size_t)(m0 + r0) * lda + kb0 * 8;
    const unsigned short* Bp = Wt + (size_t)(n0 + r0) * ldw + kb0 * 8;

    f32x4 acc[4][4];
#pragma unroll
    for (int mf = 0; mf < 4; ++mf)
#pragma unroll
        for (int nf = 0; nf < 4; ++nf)
#pragma unroll
            for (int j = 0; j < 4; ++j) acc[mf][nf][j] = 0.f;

    const int arow = wm * 64 + (l & 15);
    const int brow = wn * 64 + (l & 15);
    const int kq   = l >> 4;

    for (int k0 = 0; k0 < Kdim; k0 += 32) {
        short8v a0 = *(const short8v*)(Ap + k0);
        short8v a1 = *(const short8v*)(Ap + k0 + 16);
        short8v b0 = *(const short8v*)(Bp + k0);
        short8v b1 = *(const short8v*)(Bp + k0 + 16);
        __syncthreads();
        Asta[kb0 * 128 + r0]       = a0;
        Asta[(kb0 + 2) * 128 + r0] = a1;
        Bsta[kb0 * 128 + r0]       = b0;
        Bsta[(kb0 + 2) * 128 + r0] = b1;
        __syncthreads();
        short8v af[4], bfv[4];
#pragma unroll
        for (int mf = 0; mf < 4; ++mf) af[mf]  = Asta[kq * 128 + arow + mf * 16];
#pragma unroll
        for (int nf = 0; nf < 4; ++nf) bfv[nf] = Bsta[kq * 128 + brow + nf * 16];
#pragma unroll
        for (int mf = 0; mf < 4; ++mf)
#pragma unroll
            for (int nf = 0; nf < 4; ++nf)
                acc[mf][nf] = __builtin_amdgcn_mfma_f32_16x16x32_bf16(
                    af[mf], bfv[nf], acc[mf][nf], 0, 0, 0);
    }

    float s[4], sh[4];
    int cols[4];
#pragma unroll
    for (int nf = 0; nf < 4; ++nf) {
        int col = n0 + wn * 64 + nf * 16 + (l & 15);
        cols[nf] = col;
        if (EPI == 2) { s[nf] = 1.f; sh[nf] = bias[col]; }
        else {
            float sc = bng[col] * rsqrtf(bnv[col] + BN_EPS);
            s[nf]  = sc;
            sh[nf] = bnb[col] - bnm[col] * sc;
        }
    }
#pragma unroll
    for (int mf = 0; mf < 4; ++mf) {
#pragma unroll
        for (int j = 0; j < 4; ++j) {
            int row = m0 + wm * 64 + mf * 16 + kq * 4 + j;
#pragma unroll
            for (int nf = 0; nf < 4; ++nf) {
                float v = acc[mf][nf][j] * s[nf] + sh[nf];
                if (EPI == 1) v += b2f(res[(size_t)row * ldres + cols[nf]]);
                if (EPI != 2) v = fmaxf(v, 0.f);
                if (EPI == 2) {
                    ((float*)outp)[(size_t)row * ldc + cols[nf]] = v;
                } else if (EPI == 3) {
                    int b = row >> 10, h = (row >> 5) & 31, ww = row & 31;
                    size_t pidx = ((size_t)(b * 36 + h + 2) * 36 + (ww + 2)) * 128 + cols[nf];
                    ((unsigned short*)outp)[pidx] = f2b(v);
                } else {
                    ((unsigned short*)outp)[(size_t)row * ldc + cols[nf]] = f2b(v);
                }
            }
        }
    }
}

// ---------------------------------------------------------------------------
// Both 3x3 convs: tile 64 rows x 128 oc, full K=128 staged per tap (one
// barrier pair per tap, 32 MFMA/wave between). grid (256, 2): y = branch.
// opad: [16][36][36][128] bf16, pad=2. wt[branch][tap][oc][ic] bf16.
// ---------------------------------------------------------------------------
__global__ __launch_bounds__(256) void conv_mfma(
    const unsigned short* __restrict__ opad,
    const unsigned short* __restrict__ wt_all,
    const float* __restrict__ g1, const float* __restrict__ b1,
    const float* __restrict__ m1, const float* __restrict__ v1,
    const float* __restrict__ g2, const float* __restrict__ b2,
    const float* __restrict__ m2, const float* __restrict__ v2,
    unsigned short* __restrict__ lg)
{
    __shared__ short8v Asta[1024];   // [kb 0..15][row 0..63]
    __shared__ short8v Bsta[2048];   // [kb 0..15][oc 0..127]
    const int t = threadIdx.x;
    const int l = t & 63, w = t >> 6;
    const int wm = w >> 1, wn = w & 1;
    const int m0 = blockIdx.x << 6;
    const int br = blockIdx.y;
    const int dil = 1 + br;
    const unsigned short* wtb = wt_all + (size_t)br * 147456;

    const int r0  = t & 63,  kb0 = t >> 6;    // A: chunks kb0 + 4i, i=0..3
    const int rb  = t & 127, kbb = t >> 7;    // B: chunks kbb + 2i, i=0..7
    const int m   = m0 + r0;
    const int bb  = m >> 10, h = (m >> 5) & 31, wc = m & 31;
    const ptrdiff_t pbase = ((ptrdiff_t)(bb * 36 + h + 2) * 36 + (wc + 2)) * 128;

    f32x4 acc[2][4];
#pragma unroll
    for (int mf = 0; mf < 2; ++mf)
#pragma unroll
        for (int nf = 0; nf < 4; ++nf)
#pragma unroll
            for (int j = 0; j < 4; ++j) acc[mf][nf][j] = 0.f;

    const int arow = wm * 32 + (l & 15);
    const int bcol = wn * 64 + (l & 15);
    const int kq   = l >> 4;

    for (int tap = 0; tap < 9; ++tap) {
        const int dh = tap / 3 - 1, dw = tap % 3 - 1;
        const unsigned short* Ap = opad + pbase + (ptrdiff_t)((dh * 36 + dw) * dil) * 128;
        const unsigned short* Bp = wtb + (size_t)tap * 16384 + (size_t)rb * 128;
        short8v av[4], bv[8];
#pragma unroll
        for (int i = 0; i < 4; ++i) av[i] = *(const short8v*)(Ap + (kb0 + 4 * i) * 8);
#pragma unroll
        for (int i = 0; i < 8; ++i) bv[i] = *(const short8v*)(Bp + (kbb + 2 * i) * 8);
        __syncthreads();
#pragma unroll
        for (int i = 0; i < 4; ++i) Asta[(kb0 + 4 * i) * 64 + r0] = av[i];
#pragma unroll
        for (int i = 0; i < 8; ++i) Bsta[(kbb + 2 * i) * 128 + rb] = bv[i];
        __syncthreads();
#pragma unroll
        for (int kk = 0; kk < 4; ++kk) {
            short8v af[2], bfv[4];
            af[0] = Asta[(kq + 4 * kk) * 64 + arow];
            af[1] = Asta[(kq + 4 * kk) * 64 + arow + 16];
#pragma unroll
            for (int nf = 0; nf < 4; ++nf)
                bfv[nf] = Bsta[(kq + 4 * kk) * 128 + bcol + nf * 16];
#pragma unroll
            for (int mf = 0; mf < 2; ++mf)
#pragma unroll
                for (int nf = 0; nf < 4; ++nf)
                    acc[mf][nf] = __builtin_amdgcn_mfma_f32_16x16x32_bf16(
                        af[mf], bfv[nf], acc[mf][nf], 0, 0, 0);
        }
    }

    const float* gg = br ? g2 : g1;
    const float* gb = br ? b2 : b1;
    const float* gm = br ? m2 : m1;
    const float* gv = br ? v2 : v1;
    float s[4], sh[4];
    int cols[4];
#pragma unroll
    for (int nf = 0; nf < 4; ++nf) {
        int col = bcol + nf * 16;
        cols[nf] = col;
        float sc = gg[col] * rsqrtf(gv[col] + BN_EPS);
        s[nf]  = sc;
        sh[nf] = gb[col] - gm[col] * sc;
    }
#pragma unroll
    for (int mf = 0; mf < 2; ++mf) {
#pragma unroll
        for (int j = 0; j < 4; ++j) {
            int row = m0 + wm * 32 + mf * 16 + kq * 4 + j;
#pragma unroll
            for (int nf = 0; nf < 4; ++nf) {
                float v = fmaxf(acc[mf][nf][j] * s[nf] + sh[nf], 0.f);
                lg[(size_t)row * 256 + br * 128 + cols[nf]] = f2b(v);
            }
        }
    }
}

// ---------------------------------------------------------------------------
// L2-normalize rows of fp32 [16384][512] in place; also write bf16 copy.
// ---------------------------------------------------------------------------
__global__ __launch_bounds__(256) void l2norm_rows(
    float* __restrict__ x, unsigned short* __restrict__ xn)
{
    const int t    = threadIdx.x;
    const int wv   = t >> 6, lane = t & 63;
    const int row  = (blockIdx.x << 2) + wv;
    float* p = x + (size_t)row * 512 + (lane << 3);
    float4 a = *(float4*)p;
    float4 b = *(float4*)(p + 4);
    float ss = a.x * a.x + a.y * a.y + a.z * a.z + a.w * a.w +
               b.x * b.x + b.y * b.y + b.z * b.z + b.w * b.w;
#pragma unroll
    for (int off = 32; off >= 1; off >>= 1) ss += __shfl_xor(ss, off);
    float sc = 1.f / fmaxf(sqrtf(ss), 1e-12f);
    a.x *= sc; a.y *= sc; a.z *= sc; a.w *= sc;
    b.x *= sc; b.y *= sc; b.z *= sc; b.w *= sc;
    *(float4*)p       = a;
    *(float4*)(p + 4) = b;
    ushort8v r;
    r[0] = f2b(a.x); r[1] = f2b(a.y); r[2] = f2b(a.z); r[3] = f2b(a.w);
    r[4] = f2b(b.x); r[5] = f2b(b.y); r[6] = f2b(b.z); r[7] = f2b(b.w);
    *(ushort8v*)(xn + (size_t)row * 512 + (lane << 3)) = r;
}

// ---------------------------------------------------------------------------
// sims + per-class max: tile 128 rows x 128 protos = 2 classes per block.
// grid (128, 10). Wave (wm,wn): rows wm*64+, cols wn*64+ -> class 2y+wn.
// Epilogue: max over 4 n-frags then shfl_xor over the 16-lane col group.
// ---------------------------------------------------------------------------
__global__ __launch_bounds__(256) void sims_mfma(
    const unsigned short* __restrict__ xn,
    const unsigned short* __restrict__ protos,
    float* __restrict__ act)
{
    __shared__ short8v Asta[512];
    __shared__ short8v Bsta[512];
    const int t = threadIdx.x;
    const int l = t & 63, w = t >> 6;
    const int wm = w >> 1, wn = w & 1;
    const int m0 = blockIdx.x << 7;

    const int r0  = t & 127, kb0 = t >> 7;
    const unsigned short* Ap = xn + (size_t)(m0 + r0) * 512 + kb0 * 8;
    const unsigned short* Bp = protos + ((size_t)blockIdx.y * 128 + r0) * 512 + kb0 * 8;

    f32x4 acc[4][4];
#pragma unroll
    for (int mf = 0; mf < 4; ++mf)
#pragma unroll
        for (int nf = 0; nf < 4; ++nf)
#pragma unroll
            for (int j = 0; j < 4; ++j) acc[mf][nf][j] = 0.f;

    const int arow = wm * 64 + (l & 15);
    const int brow = wn * 64 + (l & 15);
    const int kq   = l >> 4;

    for (int k0 = 0; k0 < 512; k0 += 32) {
        short8v a0 = *(const short8v*)(Ap + k0);
        short8v a1 = *(const short8v*)(Ap + k0 + 16);
        short8v b0 = *(const short8v*)(Bp + k0);
        short8v b1 = *(const short8v*)(Bp + k0 + 16);
        __syncthreads();
        Asta[kb0 * 128 + r0]       = a0;
        Asta[(kb0 + 2) * 128 + r0] = a1;
        Bsta[kb0 * 128 + r0]       = b0;
        Bsta[(kb0 + 2) * 128 + r0] = b1;
        __syncthreads();
        short8v af[4], bfv[4];
#pragma unroll
        for (int mf = 0; mf < 4; ++mf) af[mf]  = Asta[kq * 128 + arow + mf * 16];
#pragma unroll
        for (int nf = 0; nf < 4; ++nf) bfv[nf] = Bsta[kq * 128 + brow + nf * 16];
#pragma unroll
        for (int mf = 0; mf < 4; ++mf)
#pragma unroll
            for (int nf = 0; nf < 4; ++nf)
                acc[mf][nf] = __builtin_amdgcn_mfma_f32_16x16x32_bf16(
                    af[mf], bfv[nf], acc[mf][nf], 0, 0, 0);
    }

    const int c = (blockIdx.y << 1) + wn;  // this wave's class
#pragma unroll
    for (int mf = 0; mf < 4; ++mf) {
        float vj[4];
#pragma unroll
        for (int j = 0; j < 4; ++j) {
            float v = fmaxf(fmaxf(acc[mf][0][j], acc[mf][1][j]),
                            fmaxf(acc[mf][2][j], acc[mf][3][j]));
            v = fmaxf(v, __shfl_xor(v, 1));
            v = fmaxf(v, __shfl_xor(v, 2));
            v = fmaxf(v, __shfl_xor(v, 4));
            v = fmaxf(v, __shfl_xor(v, 8));
            vj[j] = v;
        }
        if ((l & 15) == 0) {
            int rowb = m0 + wm * 64 + mf * 16 + kq * 4;
#pragma unroll
            for (int j = 0; j < 4; ++j) {
                int row = rowb + j;
                int bb = row >> 10, n = row & 1023;
                act[(((size_t)(bb * 20 + c)) << 10) + n] = vj[j];
            }
        }
    }
}

// ---------------------------------------------------------------------------
__global__ __launch_bounds__(256) void logits_max(
    const float* __restrict__ act, const float* __restrict__ lsc,
    float* __restrict__ logits)
{
    const int bc = blockIdx.x;
    const int t  = threadIdx.x;
    float4 v = *(const float4*)(act + ((size_t)bc << 10) + (t << 2));
    float mx = fmaxf(fmaxf(v.x, v.y), fmaxf(v.z, v.w));
#pragma unroll
    for (int off = 32; off >= 1; off >>= 1) mx = fmaxf(mx, __shfl_xor(mx, off));
    __shared__ float wm[4];
    if ((t & 63) == 0) wm[t >> 6] = mx;
    __syncthreads();
    if (t == 0) {
        float m2 = fmaxf(fmaxf(wm[0], wm[1]), fmaxf(wm[2], wm[3]));
        logits[bc] = m2 * lsc[0];
    }
}

// ---------------------------------------------------------------------------
extern "C" void kernel_launch(void* const* d_in, const int* in_sizes, int n_in,
                              void* d_out, int out_size, void* d_ws, size_t ws_size,
                              hipStream_t stream)
{
    const float* pf   = (const float*)d_in[0];
    const float* prot = (const float*)d_in[1];
    const float* w0   = (const float*)d_in[2];
    const float* g0   = (const float*)d_in[3];
    const float* b0   = (const float*)d_in[4];
    const float* m0v  = (const float*)d_in[5];
    const float* v0   = (const float*)d_in[6];
    const float* wr   = (const float*)d_in[7];
    const float* gr   = (const float*)d_in[8];
    const float* br   = (const float*)d_in[9];
    const float* mr   = (const float*)d_in[10];
    const float* vr   = (const float*)d_in[11];
    const float* wl   = (const float*)d_in[12];
    const float* gl   = (const float*)d_in[13];
    const float* bl   = (const float*)d_in[14];
    const float* ml   = (const float*)d_in[15];
    const float* vl   = (const float*)d_in[16];
    const float* wg   = (const float*)d_in[17];
    const float* gG   = (const float*)d_in[18];
    const float* bG   = (const float*)d_in[19];
    const float* mG   = (const float*)d_in[20];
    const float* vG   = (const float*)d_in[21];
    const float* wp   = (const float*)d_in[22];
    const float* gp   = (const float*)d_in[23];
    const float* bp   = (const float*)d_in[24];
    const float* mp   = (const float*)d_in[25];
    const float* vp   = (const float*)d_in[26];
    const float* wf   = (const float*)d_in[27];
    const float* bf_  = (const float*)d_in[28];
    const float* lsc  = (const float*)d_in[29];

    char* ws = (char*)d_ws;
    unsigned short* pf_bf    = (unsigned short*)(ws);             // 25165824 B
    unsigned short* w0_bf    = (unsigned short*)(ws + 25165824);  // 786432
    unsigned short* wr_bf    = (unsigned short*)(ws + 25952256);  // 131072
    unsigned short* wt_bf    = (unsigned short*)(ws + 26083328);  // 589824
    unsigned short* wp_bf    = (unsigned short*)(ws + 26673152);  // 262144
    unsigned short* wf_bf    = (unsigned short*)(ws + 26935296);  // 524288
    unsigned short* prot_bf  = (unsigned short*)(ws + 27459584);  // 1310720
    unsigned short* x1_bf    = (unsigned short*)(ws + 28770304);  // 16777216
    unsigned short* opad     = (unsigned short*)(ws + 45547520);  // 5308416
    unsigned short* lg_bf    = (unsigned short*)(ws + 50855936);  // 8388608
    unsigned short* x2_bf    = (unsigned short*)(ws + 59244544);  // 16777216
    unsigned short* xn_bf    = (unsigned short*)(ws + 76021760);  // 16777216

    float* out    = (float*)d_out;
    float* logits = out;            // [16][20]
    float* act    = out + 320;      // [16][20][1024]
    float* xo     = out + 328000;   // [16384][512] fp32

    // ---- conversions ----
    f2b_kernel<<<6144, 256, 0, stream>>>(pf, pf_bf, 1572864);
    f2b_multi<<<736, 256, 0, stream>>>(w0, wr, wp, wf, prot,
                                       w0_bf, wr_bf, wp_bf, wf_bf, prot_bf);
    convw_kernel<<<1152, 256, 0, stream>>>(wl, wg, wt_bf);
    zero_kernel<<<1296, 256, 0, stream>>>(opad, 331776);

    // ---- adapter: pf x w0^T -> BN -> ReLU -> x1 (bf16) ----
    mfma_gemm<0><<<dim3(128, 4), 256, 0, stream>>>(
        pf_bf, 768, w0_bf, 768, x1_bf, 512, 768,
        g0, b0, m0v, v0, nullptr, 0, nullptr);

    // ---- reduce: x1 x wr^T -> BN -> ReLU -> opad (padded bf16) ----
    mfma_gemm<3><<<dim3(128, 1), 256, 0, stream>>>(
        x1_bf, 512, wr_bf, 512, opad, 0, 512,
        gr, br, mr, vr, nullptr, 0, nullptr);

    // ---- both 3x3 conv branches -> lg (bf16 [16384][256]) ----
    conv_mfma<<<dim3(256, 2), 256, 0, stream>>>(
        opad, wt_bf, gl, bl, ml, vl, gG, bG, mG, vG, lg_bf);

    // ---- project: lg x wp^T -> BN -> +x1 -> ReLU -> x2 (bf16) ----
    mfma_gemm<1><<<dim3(128, 4), 256, 0, stream>>>(
        lg_bf, 256, wp_bf, 256, x2_bf, 512, 256,
        gp, bp, mp, vp, x1_bf, 512, nullptr);

    // ---- final: x2 x wf^T + bf -> xo (fp32 in d_out) ----
    mfma_gemm<2><<<dim3(128, 4), 256, 0, stream>>>(
        x2_bf, 512, wf_bf, 512, xo, 512, 512,
        nullptr, nullptr, nullptr, nullptr, nullptr, 0, bf_);

    // ---- L2 normalize (fp32 in place) + bf16 copy ----
    l2norm_rows<<<4096, 256, 0, stream>>>(xo, xn_bf);

    // ---- sims + max over protos -> act (2 classes / block) ----
    sims_mfma<<<dim3(128, 10), 256, 0, stream>>>(xn_bf, prot_bf, act);

    // ---- logits ----
    logits_max<<<320, 256, 0, stream>>>(act, lsc, logits);
}

// Round 4
// 201.970 us; speedup vs baseline: 5.4071x; 1.0105x over previous
//
#include <hip/hip_runtime.h>
#include <math.h>

#define BN_EPS 1e-5f

typedef __attribute__((ext_vector_type(8))) short short8v;   // 8 x bf16 bits
typedef __attribute__((ext_vector_type(8))) unsigned short ushort8v;
typedef __attribute__((ext_vector_type(4))) float f32x4;

__device__ __forceinline__ unsigned short f2b(float f) {
    unsigned int u = __float_as_uint(f);
    return (unsigned short)((u + 0x7FFFu + ((u >> 16) & 1u)) >> 16);
}
__device__ __forceinline__ float b2f(unsigned short h) {
    return __uint_as_float(((unsigned int)h) << 16);
}

// async global->LDS, 16B per lane. dest must be wave-uniform base; HW writes
// base + lane*16 (guide §5: global_load_lds is NOT a per-lane scatter).
typedef __attribute__((address_space(1))) const unsigned int gas_uint;
typedef __attribute__((address_space(3))) unsigned int las_uint;
__device__ __forceinline__ void gload16(const void* g, void* l) {
    __builtin_amdgcn_global_load_lds((gas_uint*)g, (las_uint*)l, 16, 0, 0);
}

// ---------------------------------------------------------------------------
// fp32 -> bf16 convert, 8 elems/thread. n8 = n/8.
// ---------------------------------------------------------------------------
__global__ __launch_bounds__(256) void f2b_kernel(
    const float* __restrict__ in, unsigned short* __restrict__ out, int n8)
{
    int i = blockIdx.x * 256 + threadIdx.x;
    if (i >= n8) return;
    const float4* p = (const float4*)(in + (size_t)i * 8);
    float4 a = p[0], b = p[1];
    ushort8v r;
    r[0] = f2b(a.x); r[1] = f2b(a.y); r[2] = f2b(a.z); r[3] = f2b(a.w);
    r[4] = f2b(b.x); r[5] = f2b(b.y); r[6] = f2b(b.z); r[7] = f2b(b.w);
    *(ushort8v*)(out + (size_t)i * 8) = r;
}

// Fused conversion of all small weights (w0, wr, wp, wf, protos), 8/thread.
__global__ __launch_bounds__(256) void f2b_multi(
    const float* __restrict__ w0, const float* __restrict__ wr,
    const float* __restrict__ wp, const float* __restrict__ wf,
    const float* __restrict__ prot,
    unsigned short* __restrict__ w0o, unsigned short* __restrict__ wro,
    unsigned short* __restrict__ wpo, unsigned short* __restrict__ wfo,
    unsigned short* __restrict__ proto)
{
    int i = blockIdx.x * 256 + threadIdx.x;  // 188416 chunks total
    const float* src; unsigned short* dst; int off;
    if      (i <  49152) { src = w0;   dst = w0o;   off = i; }
    else if (i <  57344) { src = wr;   dst = wro;   off = i - 49152; }
    else if (i <  73728) { src = wp;   dst = wpo;   off = i - 57344; }
    else if (i < 106496) { src = wf;   dst = wfo;   off = i - 73728; }
    else if (i < 188416) { src = prot; dst = proto; off = i - 106496; }
    else return;
    const float4* p = (const float4*)(src + (size_t)off * 8);
    float4 a = p[0], b = p[1];
    ushort8v r;
    r[0] = f2b(a.x); r[1] = f2b(a.y); r[2] = f2b(a.z); r[3] = f2b(a.w);
    r[4] = f2b(b.x); r[5] = f2b(b.y); r[6] = f2b(b.z); r[7] = f2b(b.w);
    *(ushort8v*)(dst + (size_t)off * 8) = r;
}

// conv weights: w[oc][ic][3][3] fp32 -> wt[branch][tap][oc][ic] bf16
__global__ __launch_bounds__(256) void convw_kernel(
    const float* __restrict__ wl, const float* __restrict__ wg,
    unsigned short* __restrict__ out)
{
    int i = blockIdx.x * 256 + threadIdx.x;
    if (i >= 294912) return;
    int br = i >= 147456;
    int j  = i - br * 147456;
    int tap = j >> 14, oc = (j >> 7) & 127, ic = j & 127;
    const float* src = br ? wg : wl;
    out[i] = f2b(src[((oc << 7) + ic) * 9 + tap]);
}

__global__ __launch_bounds__(256) void zero_kernel(unsigned short* __restrict__ p, int n8)
{
    int i = blockIdx.x * 256 + threadIdx.x;
    if (i >= n8) return;
    ushort8v z;
#pragma unroll
    for (int k = 0; k < 8; ++k) z[k] = 0;
    *(ushort8v*)(p + (size_t)i * 8) = z;
}

// ---------------------------------------------------------------------------
// bf16 MFMA NT GEMM: C[M][Nc] = A[M][K] * W[Nc][K]^T
// Tile 128x128, BK=32, 256 threads (4 waves, 2x2), 4x4 fragments/wave.
// Staging via global_load_lds (LDS layout linear in threadIdx).
// EPI 0: BN+ReLU->bf16  1: BN+res+ReLU->bf16  2: +bias->fp32  3: BN+ReLU->padded
// ---------------------------------------------------------------------------
template <int EPI>
__global__ __launch_bounds__(256) void mfma_gemm(
    const unsigned short* __restrict__ A, int lda,
    const unsigned short* __restrict__ Wt, int ldw,
    void* __restrict__ outp, int ldc, int Kdim,
    const float* __restrict__ bng, const float* __restrict__ bnb,
    const float* __restrict__ bnm, const float* __restrict__ bnv,
    const unsigned short* __restrict__ res, int ldres,
    const float* __restrict__ bias)
{
    __shared__ short8v Asta[512];
    __shared__ short8v Bsta[512];
    const int t  = threadIdx.x;
    const int l  = t & 63, wv = t >> 6;
    const int wm = wv >> 1, wn = wv & 1;
    const int m0 = blockIdx.x << 7, n0 = blockIdx.y << 7;

    const int r0  = t & 127;
    const int kb0 = t >> 7;

    const unsigned short* Ap = A  + (size_t)(m0 + r0) * lda + kb0 * 8;
    const unsigned short* Bp = Wt + (size_t)(n0 + r0) * ldw + kb0 * 8;

    // wave-uniform LDS staging bases (element = 16B)
    short8v* aD0 = Asta + wv * 64;
    short8v* aD1 = Asta + wv * 64 + 256;
    short8v* bD0 = Bsta + wv * 64;
    short8v* bD1 = Bsta + wv * 64 + 256;

    f32x4 acc[4][4];
#pragma unroll
    for (int mf = 0; mf < 4; ++mf)
#pragma unroll
        for (int nf = 0; nf < 4; ++nf)
#pragma unroll
            for (int j = 0; j < 4; ++j) acc[mf][nf][j] = 0.f;

    const int arow = wm * 64 + (l & 15);
    const int brow = wn * 64 + (l & 15);
    const int kq   = l >> 4;

    for (int k0 = 0; k0 < Kdim; k0 += 32) {
        __syncthreads();
        gload16(Ap + k0,      aD0);
        gload16(Ap + k0 + 16, aD1);
        gload16(Bp + k0,      bD0);
        gload16(Bp + k0 + 16, bD1);
        __syncthreads();
        short8v af[4], bfv[4];
#pragma unroll
        for (int mf = 0; mf < 4; ++mf) af[mf]  = Asta[kq * 128 + arow + mf * 16];
#pragma unroll
        for (int nf = 0; nf < 4; ++nf) bfv[nf] = Bsta[kq * 128 + brow + nf * 16];
#pragma unroll
        for (int mf = 0; mf < 4; ++mf)
#pragma unroll
            for (int nf = 0; nf < 4; ++nf)
                acc[mf][nf] = __builtin_amdgcn_mfma_f32_16x16x32_bf16(
                    af[mf], bfv[nf], acc[mf][nf], 0, 0, 0);
    }

    float s[4], sh[4];
    int cols[4];
#pragma unroll
    for (int nf = 0; nf < 4; ++nf) {
        int col = n0 + wn * 64 + nf * 16 + (l & 15);
        cols[nf] = col;
        if (EPI == 2) { s[nf] = 1.f; sh[nf] = bias[col]; }
        else {
            float sc = bng[col] * rsqrtf(bnv[col] + BN_EPS);
            s[nf]  = sc;
            sh[nf] = bnb[col] - bnm[col] * sc;
        }
    }
#pragma unroll
    for (int mf = 0; mf < 4; ++mf) {
#pragma unroll
        for (int j = 0; j < 4; ++j) {
            int row = m0 + wm * 64 + mf * 16 + kq * 4 + j;
#pragma unroll
            for (int nf = 0; nf < 4; ++nf) {
                float v = acc[mf][nf][j] * s[nf] + sh[nf];
                if (EPI == 1) v += b2f(res[(size_t)row * ldres + cols[nf]]);
                if (EPI != 2) v = fmaxf(v, 0.f);
                if (EPI == 2) {
                    ((float*)outp)[(size_t)row * ldc + cols[nf]] = v;
                } else if (EPI == 3) {
                    int b = row >> 10, h = (row >> 5) & 31, ww = row & 31;
                    size_t pidx = ((size_t)(b * 36 + h + 2) * 36 + (ww + 2)) * 128 + cols[nf];
                    ((unsigned short*)outp)[pidx] = f2b(v);
                } else {
                    ((unsigned short*)outp)[(size_t)row * ldc + cols[nf]] = f2b(v);
                }
            }
        }
    }
}

// ---------------------------------------------------------------------------
// Both 3x3 convs: tile 64 rows x 128 oc, full K=128 staged per tap (one
// barrier pair per tap, 32 MFMA/wave between). grid (256, 2): y = branch.
// opad: [16][36][36][128] bf16, pad=2. wt[branch][tap][oc][ic] bf16.
// Staging via global_load_lds (LDS linear in threadIdx: elem t + 256*i).
// ---------------------------------------------------------------------------
__global__ __launch_bounds__(256) void conv_mfma(
    const unsigned short* __restrict__ opad,
    const unsigned short* __restrict__ wt_all,
    const float* __restrict__ g1, const float* __restrict__ b1,
    const float* __restrict__ m1, const float* __restrict__ v1,
    const float* __restrict__ g2, const float* __restrict__ b2,
    const float* __restrict__ m2, const float* __restrict__ v2,
    unsigned short* __restrict__ lg)
{
    __shared__ short8v Asta[1024];   // [kb 0..15][row 0..63]
    __shared__ short8v Bsta[2048];   // [kb 0..15][oc 0..127]
    const int t = threadIdx.x;
    const int l = t & 63, wv = t >> 6;
    const int wm = wv >> 1, wn = wv & 1;
    const int m0 = blockIdx.x << 6;
    const int br = blockIdx.y;
    const int dil = 1 + br;
    const unsigned short* wtb = wt_all + (size_t)br * 147456;

    const int r0  = t & 63,  kb0 = t >> 6;    // A: chunks kb0 + 4i, i=0..3
    const int rb  = t & 127, kbb = t >> 7;    // B: chunks kbb + 2i, i=0..7
    const int m   = m0 + r0;
    const int bb  = m >> 10, h = (m >> 5) & 31, wc = m & 31;
    const ptrdiff_t pbase = ((ptrdiff_t)(bb * 36 + h + 2) * 36 + (wc + 2)) * 128;
    const unsigned short* ApT = opad + pbase + kb0 * 8;      // per-lane
    const unsigned short* BpT = wtb + (size_t)rb * 128 + kbb * 8;

    f32x4 acc[2][4];
#pragma unroll
    for (int mf = 0; mf < 2; ++mf)
#pragma unroll
        for (int nf = 0; nf < 4; ++nf)
#pragma unroll
            for (int j = 0; j < 4; ++j) acc[mf][nf][j] = 0.f;

    const int arow = wm * 32 + (l & 15);
    const int bcol = wn * 64 + (l & 15);
    const int kq   = l >> 4;

    for (int tap = 0; tap < 9; ++tap) {
        const int dh = tap / 3 - 1, dw = tap % 3 - 1;
        const unsigned short* Ap = ApT + (ptrdiff_t)((dh * 36 + dw) * dil) * 128;
        const unsigned short* Bp = BpT + (size_t)tap * 16384;
        __syncthreads();
#pragma unroll
        for (int i = 0; i < 4; ++i)
            gload16(Ap + 32 * i, Asta + wv * 64 + 256 * i);
#pragma unroll
        for (int i = 0; i < 8; ++i)
            gload16(Bp + 16 * i, Bsta + wv * 64 + 256 * i);
        __syncthreads();
#pragma unroll
        for (int kk = 0; kk < 4; ++kk) {
            short8v af[2], bfv[4];
            af[0] = Asta[(kq + 4 * kk) * 64 + arow];
            af[1] = Asta[(kq + 4 * kk) * 64 + arow + 16];
#pragma unroll
            for (int nf = 0; nf < 4; ++nf)
                bfv[nf] = Bsta[(kq + 4 * kk) * 128 + bcol + nf * 16];
#pragma unroll
            for (int mf = 0; mf < 2; ++mf)
#pragma unroll
                for (int nf = 0; nf < 4; ++nf)
                    acc[mf][nf] = __builtin_amdgcn_mfma_f32_16x16x32_bf16(
                        af[mf], bfv[nf], acc[mf][nf], 0, 0, 0);
        }
    }

    const float* gg = br ? g2 : g1;
    const float* gb = br ? b2 : b1;
    const float* gm = br ? m2 : m1;
    const float* gv = br ? v2 : v1;
    float s[4], sh[4];
    int cols[4];
#pragma unroll
    for (int nf = 0; nf < 4; ++nf) {
        int col = bcol + nf * 16;
        cols[nf] = col;
        float sc = gg[col] * rsqrtf(gv[col] + BN_EPS);
        s[nf]  = sc;
        sh[nf] = gb[col] - gm[col] * sc;
    }
#pragma unroll
    for (int mf = 0; mf < 2; ++mf) {
#pragma unroll
        for (int j = 0; j < 4; ++j) {
            int row = m0 + wm * 32 + mf * 16 + kq * 4 + j;
#pragma unroll
            for (int nf = 0; nf < 4; ++nf) {
                float v = fmaxf(acc[mf][nf][j] * s[nf] + sh[nf], 0.f);
                lg[(size_t)row * 256 + br * 128 + cols[nf]] = f2b(v);
            }
        }
    }
}

// ---------------------------------------------------------------------------
// L2-normalize rows of fp32 [16384][512] in place; also write bf16 copy.
// ---------------------------------------------------------------------------
__global__ __launch_bounds__(256) void l2norm_rows(
    float* __restrict__ x, unsigned short* __restrict__ xn)
{
    const int t    = threadIdx.x;
    const int wv   = t >> 6, lane = t & 63;
    const int row  = (blockIdx.x << 2) + wv;
    float* p = x + (size_t)row * 512 + (lane << 3);
    float4 a = *(float4*)p;
    float4 b = *(float4*)(p + 4);
    float ss = a.x * a.x + a.y * a.y + a.z * a.z + a.w * a.w +
               b.x * b.x + b.y * b.y + b.z * b.z + b.w * b.w;
#pragma unroll
    for (int off = 32; off >= 1; off >>= 1) ss += __shfl_xor(ss, off);
    float sc = 1.f / fmaxf(sqrtf(ss), 1e-12f);
    a.x *= sc; a.y *= sc; a.z *= sc; a.w *= sc;
    b.x *= sc; b.y *= sc; b.z *= sc; b.w *= sc;
    *(float4*)p       = a;
    *(float4*)(p + 4) = b;
    ushort8v r;
    r[0] = f2b(a.x); r[1] = f2b(a.y); r[2] = f2b(a.z); r[3] = f2b(a.w);
    r[4] = f2b(b.x); r[5] = f2b(b.y); r[6] = f2b(b.z); r[7] = f2b(b.w);
    *(ushort8v*)(xn + (size_t)row * 512 + (lane << 3)) = r;
}

// ---------------------------------------------------------------------------
// sims + per-class max: tile 128 rows x 128 protos = 2 classes per block.
// grid (128, 10). Wave (wm,wn): rows wm*64+, cols wn*64+ -> class 2y+wn.
// Epilogue: max over 4 n-frags then shfl_xor over the 16-lane col group.
// ---------------------------------------------------------------------------
__global__ __launch_bounds__(256) void sims_mfma(
    const unsigned short* __restrict__ xn,
    const unsigned short* __restrict__ protos,
    float* __restrict__ act)
{
    __shared__ short8v Asta[512];
    __shared__ short8v Bsta[512];
    const int t = threadIdx.x;
    const int l = t & 63, wv = t >> 6;
    const int wm = wv >> 1, wn = wv & 1;
    const int m0 = blockIdx.x << 7;

    const int r0  = t & 127, kb0 = t >> 7;
    const unsigned short* Ap = xn + (size_t)(m0 + r0) * 512 + kb0 * 8;
    const unsigned short* Bp = protos + ((size_t)blockIdx.y * 128 + r0) * 512 + kb0 * 8;

    short8v* aD0 = Asta + wv * 64;
    short8v* aD1 = Asta + wv * 64 + 256;
    short8v* bD0 = Bsta + wv * 64;
    short8v* bD1 = Bsta + wv * 64 + 256;

    f32x4 acc[4][4];
#pragma unroll
    for (int mf = 0; mf < 4; ++mf)
#pragma unroll
        for (int nf = 0; nf < 4; ++nf)
#pragma unroll
            for (int j = 0; j < 4; ++j) acc[mf][nf][j] = 0.f;

    const int arow = wm * 64 + (l & 15);
    const int brow = wn * 64 + (l & 15);
    const int kq   = l >> 4;

    for (int k0 = 0; k0 < 512; k0 += 32) {
        __syncthreads();
        gload16(Ap + k0,      aD0);
        gload16(Ap + k0 + 16, aD1);
        gload16(Bp + k0,      bD0);
        gload16(Bp + k0 + 16, bD1);
        __syncthreads();
        short8v af[4], bfv[4];
#pragma unroll
        for (int mf = 0; mf < 4; ++mf) af[mf]  = Asta[kq * 128 + arow + mf * 16];
#pragma unroll
        for (int nf = 0; nf < 4; ++nf) bfv[nf] = Bsta[kq * 128 + brow + nf * 16];
#pragma unroll
        for (int mf = 0; mf < 4; ++mf)
#pragma unroll
            for (int nf = 0; nf < 4; ++nf)
                acc[mf][nf] = __builtin_amdgcn_mfma_f32_16x16x32_bf16(
                    af[mf], bfv[nf], acc[mf][nf], 0, 0, 0);
    }

    const int c = (blockIdx.y << 1) + wn;  // this wave's class
#pragma unroll
    for (int mf = 0; mf < 4; ++mf) {
        float vj[4];
#pragma unroll
        for (int j = 0; j < 4; ++j) {
            float v = fmaxf(fmaxf(acc[mf][0][j], acc[mf][1][j]),
                            fmaxf(acc[mf][2][j], acc[mf][3][j]));
            v = fmaxf(v, __shfl_xor(v, 1));
            v = fmaxf(v, __shfl_xor(v, 2));
            v = fmaxf(v, __shfl_xor(v, 4));
            v = fmaxf(v, __shfl_xor(v, 8));
            vj[j] = v;
        }
        if ((l & 15) == 0) {
            int rowb = m0 + wm * 64 + mf * 16 + kq * 4;
#pragma unroll
            for (int j = 0; j < 4; ++j) {
                int row = rowb + j;
                int bb = row >> 10, n = row & 1023;
                act[(((size_t)(bb * 20 + c)) << 10) + n] = vj[j];
            }
        }
    }
}

// ---------------------------------------------------------------------------
__global__ __launch_bounds__(256) void logits_max(
    const float* __restrict__ act, const float* __restrict__ lsc,
    float* __restrict__ logits)
{
    const int bc = blockIdx.x;
    const int t  = threadIdx.x;
    float4 v = *(const float4*)(act + ((size_t)bc << 10) + (t << 2));
    float mx = fmaxf(fmaxf(v.x, v.y), fmaxf(v.z, v.w));
#pragma unroll
    for (int off = 32; off >= 1; off >>= 1) mx = fmaxf(mx, __shfl_xor(mx, off));
    __shared__ float wmred[4];
    if ((t & 63) == 0) wmred[t >> 6] = mx;
    __syncthreads();
    if (t == 0) {
        float m2 = fmaxf(fmaxf(wmred[0], wmred[1]), fmaxf(wmred[2], wmred[3]));
        logits[bc] = m2 * lsc[0];
    }
}

// ---------------------------------------------------------------------------
extern "C" void kernel_launch(void* const* d_in, const int* in_sizes, int n_in,
                              void* d_out, int out_size, void* d_ws, size_t ws_size,
                              hipStream_t stream)
{
    const float* pf   = (const float*)d_in[0];
    const float* prot = (const float*)d_in[1];
    const float* w0   = (const float*)d_in[2];
    const float* g0   = (const float*)d_in[3];
    const float* b0   = (const float*)d_in[4];
    const float* m0v  = (const float*)d_in[5];
    const float* v0   = (const float*)d_in[6];
    const float* wr   = (const float*)d_in[7];
    const float* gr   = (const float*)d_in[8];
    const float* br   = (const float*)d_in[9];
    const float* mr   = (const float*)d_in[10];
    const float* vr   = (const float*)d_in[11];
    const float* wl   = (const float*)d_in[12];
    const float* gl   = (const float*)d_in[13];
    const float* bl   = (const float*)d_in[14];
    const float* ml   = (const float*)d_in[15];
    const float* vl   = (const float*)d_in[16];
    const float* wg   = (const float*)d_in[17];
    const float* gG   = (const float*)d_in[18];
    const float* bG   = (const float*)d_in[19];
    const float* mG   = (const float*)d_in[20];
    const float* vG   = (const float*)d_in[21];
    const float* wp   = (const float*)d_in[22];
    const float* gp   = (const float*)d_in[23];
    const float* bp   = (const float*)d_in[24];
    const float* mp   = (const float*)d_in[25];
    const float* vp   = (const float*)d_in[26];
    const float* wf   = (const float*)d_in[27];
    const float* bf_  = (const float*)d_in[28];
    const float* lsc  = (const float*)d_in[29];

    char* ws = (char*)d_ws;
    unsigned short* pf_bf    = (unsigned short*)(ws);             // 25165824 B
    unsigned short* w0_bf    = (unsigned short*)(ws + 25165824);  // 786432
    unsigned short* wr_bf    = (unsigned short*)(ws + 25952256);  // 131072
    unsigned short* wt_bf    = (unsigned short*)(ws + 26083328);  // 589824
    unsigned short* wp_bf    = (unsigned short*)(ws + 26673152);  // 262144
    unsigned short* wf_bf    = (unsigned short*)(ws + 26935296);  // 524288
    unsigned short* prot_bf  = (unsigned short*)(ws + 27459584);  // 1310720
    unsigned short* x1_bf    = (unsigned short*)(ws + 28770304);  // 16777216
    unsigned short* opad     = (unsigned short*)(ws + 45547520);  // 5308416
    unsigned short* lg_bf    = (unsigned short*)(ws + 50855936);  // 8388608
    unsigned short* x2_bf    = (unsigned short*)(ws + 59244544);  // 16777216
    unsigned short* xn_bf    = (unsigned short*)(ws + 76021760);  // 16777216

    float* out    = (float*)d_out;
    float* logits = out;            // [16][20]
    float* act    = out + 320;      // [16][20][1024]
    float* xo     = out + 328000;   // [16384][512] fp32

    // ---- conversions ----
    f2b_kernel<<<6144, 256, 0, stream>>>(pf, pf_bf, 1572864);
    f2b_multi<<<736, 256, 0, stream>>>(w0, wr, wp, wf, prot,
                                       w0_bf, wr_bf, wp_bf, wf_bf, prot_bf);
    convw_kernel<<<1152, 256, 0, stream>>>(wl, wg, wt_bf);
    zero_kernel<<<1296, 256, 0, stream>>>(opad, 331776);

    // ---- adapter: pf x w0^T -> BN -> ReLU -> x1 (bf16) ----
    mfma_gemm<0><<<dim3(128, 4), 256, 0, stream>>>(
        pf_bf, 768, w0_bf, 768, x1_bf, 512, 768,
        g0, b0, m0v, v0, nullptr, 0, nullptr);

    // ---- reduce: x1 x wr^T -> BN -> ReLU -> opad (padded bf16) ----
    mfma_gemm<3><<<dim3(128, 1), 256, 0, stream>>>(
        x1_bf, 512, wr_bf, 512, opad, 0, 512,
        gr, br, mr, vr, nullptr, 0, nullptr);

    // ---- both 3x3 conv branches -> lg (bf16 [16384][256]) ----
    conv_mfma<<<dim3(256, 2), 256, 0, stream>>>(
        opad, wt_bf, gl, bl, ml, vl, gG, bG, mG, vG, lg_bf);

    // ---- project: lg x wp^T -> BN -> +x1 -> ReLU -> x2 (bf16) ----
    mfma_gemm<1><<<dim3(128, 4), 256, 0, stream>>>(
        lg_bf, 256, wp_bf, 256, x2_bf, 512, 256,
        gp, bp, mp, vp, x1_bf, 512, nullptr);

    // ---- final: x2 x wf^T + bf -> xo (fp32 in d_out) ----
    mfma_gemm<2><<<dim3(128, 4), 256, 0, stream>>>(
        x2_bf, 512, wf_bf, 512, xo, 512, 512,
        nullptr, nullptr, nullptr, nullptr, nullptr, 0, bf_);

    // ---- L2 normalize (fp32 in place) + bf16 copy ----
    l2norm_rows<<<4096, 256, 0, stream>>>(xo, xn_bf);

    // ---- sims + max over protos -> act (2 classes / block) ----
    sims_mfma<<<dim3(128, 10), 256, 0, stream>>>(xn_bf, prot_bf, act);

    // ---- logits ----
    logits_max<<<320, 256, 0, stream>>>(act, lsc, logits);
}

// Round 5
// 197.978 us; speedup vs baseline: 5.5161x; 1.0202x over previous
//
#include <hip/hip_runtime.h>
#include <math.h>

#define BN_EPS 1e-5f

typedef __attribute__((ext_vector_type(8))) short short8v;   // 8 x bf16 bits
typedef __attribute__((ext_vector_type(8))) unsigned short ushort8v;
typedef __attribute__((ext_vector_type(4))) float f32x4;

__device__ __forceinline__ unsigned short f2b(float f) {
    unsigned int u = __float_as_uint(f);
    return (unsigned short)((u + 0x7FFFu + ((u >> 16) & 1u)) >> 16);
}
__device__ __forceinline__ float b2f(unsigned short h) {
    return __uint_as_float(((unsigned int)h) << 16);
}

// async global->LDS, 16B per lane. dest must be wave-uniform base; HW writes
// base + lane*16 (guide §5: global_load_lds is NOT a per-lane scatter).
typedef __attribute__((address_space(1))) const unsigned int gas_uint;
typedef __attribute__((address_space(3))) unsigned int las_uint;
__device__ __forceinline__ void gload16(const void* g, void* l) {
    __builtin_amdgcn_global_load_lds((gas_uint*)g, (las_uint*)l, 16, 0, 0);
}

// ---------------------------------------------------------------------------
// fp32 -> bf16 convert, 8 elems/thread. n8 = n/8.
// ---------------------------------------------------------------------------
__global__ __launch_bounds__(256) void f2b_kernel(
    const float* __restrict__ in, unsigned short* __restrict__ out, int n8)
{
    int i = blockIdx.x * 256 + threadIdx.x;
    if (i >= n8) return;
    const float4* p = (const float4*)(in + (size_t)i * 8);
    float4 a = p[0], b = p[1];
    ushort8v r;
    r[0] = f2b(a.x); r[1] = f2b(a.y); r[2] = f2b(a.z); r[3] = f2b(a.w);
    r[4] = f2b(b.x); r[5] = f2b(b.y); r[6] = f2b(b.z); r[7] = f2b(b.w);
    *(ushort8v*)(out + (size_t)i * 8) = r;
}

// Fused conversion of all small weights (w0, wr, wp, wf, protos), 8/thread.
__global__ __launch_bounds__(256) void f2b_multi(
    const float* __restrict__ w0, const float* __restrict__ wr,
    const float* __restrict__ wp, const float* __restrict__ wf,
    const float* __restrict__ prot,
    unsigned short* __restrict__ w0o, unsigned short* __restrict__ wro,
    unsigned short* __restrict__ wpo, unsigned short* __restrict__ wfo,
    unsigned short* __restrict__ proto)
{
    int i = blockIdx.x * 256 + threadIdx.x;  // 188416 chunks total
    const float* src; unsigned short* dst; int off;
    if      (i <  49152) { src = w0;   dst = w0o;   off = i; }
    else if (i <  57344) { src = wr;   dst = wro;   off = i - 49152; }
    else if (i <  73728) { src = wp;   dst = wpo;   off = i - 57344; }
    else if (i < 106496) { src = wf;   dst = wfo;   off = i - 73728; }
    else if (i < 188416) { src = prot; dst = proto; off = i - 106496; }
    else return;
    const float4* p = (const float4*)(src + (size_t)off * 8);
    float4 a = p[0], b = p[1];
    ushort8v r;
    r[0] = f2b(a.x); r[1] = f2b(a.y); r[2] = f2b(a.z); r[3] = f2b(a.w);
    r[4] = f2b(b.x); r[5] = f2b(b.y); r[6] = f2b(b.z); r[7] = f2b(b.w);
    *(ushort8v*)(dst + (size_t)off * 8) = r;
}

// conv weights: w[oc][ic][3][3] fp32 -> wt[branch][tap][oc][ic] bf16
__global__ __launch_bounds__(256) void convw_kernel(
    const float* __restrict__ wl, const float* __restrict__ wg,
    unsigned short* __restrict__ out)
{
    int i = blockIdx.x * 256 + threadIdx.x;
    if (i >= 294912) return;
    int br = i >= 147456;
    int j  = i - br * 147456;
    int tap = j >> 14, oc = (j >> 7) & 127, ic = j & 127;
    const float* src = br ? wg : wl;
    out[i] = f2b(src[((oc << 7) + ic) * 9 + tap]);
}

__global__ __launch_bounds__(256) void zero_kernel(unsigned short* __restrict__ p, int n8)
{
    int i = blockIdx.x * 256 + threadIdx.x;
    if (i >= n8) return;
    ushort8v z;
#pragma unroll
    for (int k = 0; k < 8; ++k) z[k] = 0;
    *(ushort8v*)(p + (size_t)i * 8) = z;
}

// ---------------------------------------------------------------------------
// bf16 MFMA NT GEMM: C[M][Nc] = A[M][K] * W[Nc][K]^T
// Tile 128x128, BK=32, 256 threads (4 waves, 2x2), 4x4 fragments/wave.
// Double-buffered LDS, ONE barrier per K-step, prefetch overlapped w/ MFMA.
// EPI 0: BN+ReLU->bf16  1: BN+res+ReLU->bf16  2: +bias->fp32  3: BN+ReLU->padded
// ---------------------------------------------------------------------------
template <int EPI>
__global__ __launch_bounds__(256, 3) void mfma_gemm(
    const unsigned short* __restrict__ A, int lda,
    const unsigned short* __restrict__ Wt, int ldw,
    void* __restrict__ outp, int ldc, int Kdim,
    const float* __restrict__ bng, const float* __restrict__ bnb,
    const float* __restrict__ bnm, const float* __restrict__ bnv,
    const unsigned short* __restrict__ res, int ldres,
    const float* __restrict__ bias)
{
    __shared__ short8v Asta[2][512];
    __shared__ short8v Bsta[2][512];
    const int t  = threadIdx.x;
    const int l  = t & 63, wv = t >> 6;
    const int wm = wv >> 1, wn = wv & 1;
    const int m0 = blockIdx.x << 7, n0 = blockIdx.y << 7;

    const int r0  = t & 127;
    const int kb0 = t >> 7;

    const unsigned short* Ap = A  + (size_t)(m0 + r0) * lda + kb0 * 8;
    const unsigned short* Bp = Wt + (size_t)(n0 + r0) * ldw + kb0 * 8;

    f32x4 acc[4][4];
#pragma unroll
    for (int mf = 0; mf < 4; ++mf)
#pragma unroll
        for (int nf = 0; nf < 4; ++nf)
#pragma unroll
            for (int j = 0; j < 4; ++j) acc[mf][nf][j] = 0.f;

    const int arow = wm * 64 + (l & 15);
    const int brow = wn * 64 + (l & 15);
    const int kq   = l >> 4;

    const int nK = Kdim >> 5;

#define STAGE_G(buf, k0)                                     \
    do {                                                     \
        gload16(Ap + (k0),      &Asta[buf][wv * 64]);        \
        gload16(Ap + (k0) + 16, &Asta[buf][wv * 64 + 256]);  \
        gload16(Bp + (k0),      &Bsta[buf][wv * 64]);        \
        gload16(Bp + (k0) + 16, &Bsta[buf][wv * 64 + 256]);  \
    } while (0)

    STAGE_G(0, 0);
    __syncthreads();
    int cur = 0;
    for (int ks = 0; ks < nK; ++ks) {
        short8v af[4], bfv[4];
#pragma unroll
        for (int mf = 0; mf < 4; ++mf) af[mf]  = Asta[cur][kq * 128 + arow + mf * 16];
#pragma unroll
        for (int nf = 0; nf < 4; ++nf) bfv[nf] = Bsta[cur][kq * 128 + brow + nf * 16];
        if (ks + 1 < nK) STAGE_G(cur ^ 1, (ks + 1) << 5);
#pragma unroll
        for (int mf = 0; mf < 4; ++mf)
#pragma unroll
            for (int nf = 0; nf < 4; ++nf)
                acc[mf][nf] = __builtin_amdgcn_mfma_f32_16x16x32_bf16(
                    af[mf], bfv[nf], acc[mf][nf], 0, 0, 0);
        __syncthreads();
        cur ^= 1;
    }
#undef STAGE_G

    float s[4], sh[4];
    int cols[4];
#pragma unroll
    for (int nf = 0; nf < 4; ++nf) {
        int col = n0 + wn * 64 + nf * 16 + (l & 15);
        cols[nf] = col;
        if (EPI == 2) { s[nf] = 1.f; sh[nf] = bias[col]; }
        else {
            float sc = bng[col] * rsqrtf(bnv[col] + BN_EPS);
            s[nf]  = sc;
            sh[nf] = bnb[col] - bnm[col] * sc;
        }
    }
#pragma unroll
    for (int mf = 0; mf < 4; ++mf) {
#pragma unroll
        for (int j = 0; j < 4; ++j) {
            int row = m0 + wm * 64 + mf * 16 + kq * 4 + j;
#pragma unroll
            for (int nf = 0; nf < 4; ++nf) {
                float v = acc[mf][nf][j] * s[nf] + sh[nf];
                if (EPI == 1) v += b2f(res[(size_t)row * ldres + cols[nf]]);
                if (EPI != 2) v = fmaxf(v, 0.f);
                if (EPI == 2) {
                    ((float*)outp)[(size_t)row * ldc + cols[nf]] = v;
                } else if (EPI == 3) {
                    int b = row >> 10, h = (row >> 5) & 31, ww = row & 31;
                    size_t pidx = ((size_t)(b * 36 + h + 2) * 36 + (ww + 2)) * 128 + cols[nf];
                    ((unsigned short*)outp)[pidx] = f2b(v);
                } else {
                    ((unsigned short*)outp)[(size_t)row * ldc + cols[nf]] = f2b(v);
                }
            }
        }
    }
}

// ---------------------------------------------------------------------------
// Both 3x3 convs: tile 64 rows x 128 oc. 18 pipeline stages (9 taps x 2
// K=64 halves), double-buffered LDS, one barrier per stage, prefetch
// overlapped with MFMA. grid (256, 2): y = branch (dil = 1+y).
// opad: [16][36][36][128] bf16, pad=2. wt[branch][tap][oc][ic] bf16.
// ---------------------------------------------------------------------------
__global__ __launch_bounds__(256, 3) void conv_mfma(
    const unsigned short* __restrict__ opad,
    const unsigned short* __restrict__ wt_all,
    const float* __restrict__ g1, const float* __restrict__ b1,
    const float* __restrict__ m1, const float* __restrict__ v1,
    const float* __restrict__ g2, const float* __restrict__ b2,
    const float* __restrict__ m2, const float* __restrict__ v2,
    unsigned short* __restrict__ lg)
{
    __shared__ short8v Asta[2][512];    // [kb 0..7][row 0..63]
    __shared__ short8v Bsta[2][1024];   // [kb 0..7][oc 0..127]
    const int t = threadIdx.x;
    const int l = t & 63, wv = t >> 6;
    const int wm = wv >> 1, wn = wv & 1;
    const int m0 = blockIdx.x << 6;
    const int br = blockIdx.y;
    const int dil = 1 + br;
    const unsigned short* wtb = wt_all + (size_t)br * 147456;

    const int r0 = t & 63;
    const int m  = m0 + r0;
    const int bb = m >> 10, h = (m >> 5) & 31, wc = m & 31;
    const ptrdiff_t pbase = ((ptrdiff_t)(bb * 36 + h + 2) * 36 + (wc + 2)) * 128;
    const unsigned short* ApT = opad + pbase + (t >> 6) * 8;           // per-lane
    const unsigned short* BpT = wtb + (size_t)(t & 127) * 128 + (t >> 7) * 8;

    f32x4 acc[2][4];
#pragma unroll
    for (int mf = 0; mf < 2; ++mf)
#pragma unroll
        for (int nf = 0; nf < 4; ++nf)
#pragma unroll
            for (int j = 0; j < 4; ++j) acc[mf][nf][j] = 0.f;

    const int arow = wm * 32 + (l & 15);
    const int bcol = wn * 64 + (l & 15);
    const int kq   = l >> 4;

    // stage s: tap = s>>1, K-half = s&1
#define STAGE_C(buf, s)                                                        \
    do {                                                                       \
        int tap_ = (s) >> 1, hh_ = ((s) & 1) * 64;                             \
        int dh_ = tap_ / 3 - 1, dw_ = tap_ % 3 - 1;                            \
        const unsigned short* Ap_ = ApT + (ptrdiff_t)((dh_ * 36 + dw_) * dil) * 128 + hh_; \
        const unsigned short* Bp_ = BpT + (size_t)tap_ * 16384 + hh_;          \
        gload16(Ap_,      &Asta[buf][wv * 64]);                                \
        gload16(Ap_ + 32, &Asta[buf][wv * 64 + 256]);                          \
        gload16(Bp_,      &Bsta[buf][wv * 64]);                                \
        gload16(Bp_ + 16, &Bsta[buf][wv * 64 + 256]);                          \
        gload16(Bp_ + 32, &Bsta[buf][wv * 64 + 512]);                          \
        gload16(Bp_ + 48, &Bsta[buf][wv * 64 + 768]);                          \
    } while (0)

    STAGE_C(0, 0);
    __syncthreads();
    int cur = 0;
    for (int s = 0; s < 18; ++s) {
        short8v af[2][2], bfv[2][4];
#pragma unroll
        for (int kk = 0; kk < 2; ++kk) {
            int kb = kk * 4 + kq;
            af[kk][0] = Asta[cur][kb * 64 + arow];
            af[kk][1] = Asta[cur][kb * 64 + arow + 16];
#pragma unroll
            for (int nf = 0; nf < 4; ++nf)
                bfv[kk][nf] = Bsta[cur][kb * 128 + bcol + nf * 16];
        }
        if (s + 1 < 18) STAGE_C(cur ^ 1, s + 1);
#pragma unroll
        for (int kk = 0; kk < 2; ++kk)
#pragma unroll
            for (int mf = 0; mf < 2; ++mf)
#pragma unroll
                for (int nf = 0; nf < 4; ++nf)
                    acc[mf][nf] = __builtin_amdgcn_mfma_f32_16x16x32_bf16(
                        af[kk][mf], bfv[kk][nf], acc[mf][nf], 0, 0, 0);
        __syncthreads();
        cur ^= 1;
    }
#undef STAGE_C

    const float* gg = br ? g2 : g1;
    const float* gb = br ? b2 : b1;
    const float* gm = br ? m2 : m1;
    const float* gv = br ? v2 : v1;
    float s4[4], sh[4];
    int cols[4];
#pragma unroll
    for (int nf = 0; nf < 4; ++nf) {
        int col = bcol + nf * 16;
        cols[nf] = col;
        float sc = gg[col] * rsqrtf(gv[col] + BN_EPS);
        s4[nf] = sc;
        sh[nf] = gb[col] - gm[col] * sc;
    }
#pragma unroll
    for (int mf = 0; mf < 2; ++mf) {
#pragma unroll
        for (int j = 0; j < 4; ++j) {
            int row = m0 + wm * 32 + mf * 16 + kq * 4 + j;
#pragma unroll
            for (int nf = 0; nf < 4; ++nf) {
                float v = fmaxf(acc[mf][nf][j] * s4[nf] + sh[nf], 0.f);
                lg[(size_t)row * 256 + br * 128 + cols[nf]] = f2b(v);
            }
        }
    }
}

// ---------------------------------------------------------------------------
// L2-normalize rows of fp32 [16384][512] in place; also write bf16 copy.
// ---------------------------------------------------------------------------
__global__ __launch_bounds__(256) void l2norm_rows(
    float* __restrict__ x, unsigned short* __restrict__ xn)
{
    const int t    = threadIdx.x;
    const int wv   = t >> 6, lane = t & 63;
    const int row  = (blockIdx.x << 2) + wv;
    float* p = x + (size_t)row * 512 + (lane << 3);
    float4 a = *(float4*)p;
    float4 b = *(float4*)(p + 4);
    float ss = a.x * a.x + a.y * a.y + a.z * a.z + a.w * a.w +
               b.x * b.x + b.y * b.y + b.z * b.z + b.w * b.w;
#pragma unroll
    for (int off = 32; off >= 1; off >>= 1) ss += __shfl_xor(ss, off);
    float sc = 1.f / fmaxf(sqrtf(ss), 1e-12f);
    a.x *= sc; a.y *= sc; a.z *= sc; a.w *= sc;
    b.x *= sc; b.y *= sc; b.z *= sc; b.w *= sc;
    *(float4*)p       = a;
    *(float4*)(p + 4) = b;
    ushort8v r;
    r[0] = f2b(a.x); r[1] = f2b(a.y); r[2] = f2b(a.z); r[3] = f2b(a.w);
    r[4] = f2b(b.x); r[5] = f2b(b.y); r[6] = f2b(b.z); r[7] = f2b(b.w);
    *(ushort8v*)(xn + (size_t)row * 512 + (lane << 3)) = r;
}

// ---------------------------------------------------------------------------
// sims + per-class max: tile 128 rows x 128 protos = 2 classes per block.
// grid (128, 10). Wave (wm,wn): rows wm*64+, cols wn*64+ -> class 2y+wn.
// Double-buffered pipeline like mfma_gemm.
// ---------------------------------------------------------------------------
__global__ __launch_bounds__(256, 3) void sims_mfma(
    const unsigned short* __restrict__ xn,
    const unsigned short* __restrict__ protos,
    float* __restrict__ act)
{
    __shared__ short8v Asta[2][512];
    __shared__ short8v Bsta[2][512];
    const int t = threadIdx.x;
    const int l = t & 63, wv = t >> 6;
    const int wm = wv >> 1, wn = wv & 1;
    const int m0 = blockIdx.x << 7;

    const int r0  = t & 127, kb0 = t >> 7;
    const unsigned short* Ap = xn + (size_t)(m0 + r0) * 512 + kb0 * 8;
    const unsigned short* Bp = protos + ((size_t)blockIdx.y * 128 + r0) * 512 + kb0 * 8;

    f32x4 acc[4][4];
#pragma unroll
    for (int mf = 0; mf < 4; ++mf)
#pragma unroll
        for (int nf = 0; nf < 4; ++nf)
#pragma unroll
            for (int j = 0; j < 4; ++j) acc[mf][nf][j] = 0.f;

    const int arow = wm * 64 + (l & 15);
    const int brow = wn * 64 + (l & 15);
    const int kq   = l >> 4;

#define STAGE_S(buf, k0)                                     \
    do {                                                     \
        gload16(Ap + (k0),      &Asta[buf][wv * 64]);        \
        gload16(Ap + (k0) + 16, &Asta[buf][wv * 64 + 256]);  \
        gload16(Bp + (k0),      &Bsta[buf][wv * 64]);        \
        gload16(Bp + (k0) + 16, &Bsta[buf][wv * 64 + 256]);  \
    } while (0)

    STAGE_S(0, 0);
    __syncthreads();
    int cur = 0;
    for (int ks = 0; ks < 16; ++ks) {
        short8v af[4], bfv[4];
#pragma unroll
        for (int mf = 0; mf < 4; ++mf) af[mf]  = Asta[cur][kq * 128 + arow + mf * 16];
#pragma unroll
        for (int nf = 0; nf < 4; ++nf) bfv[nf] = Bsta[cur][kq * 128 + brow + nf * 16];
        if (ks + 1 < 16) STAGE_S(cur ^ 1, (ks + 1) << 5);
#pragma unroll
        for (int mf = 0; mf < 4; ++mf)
#pragma unroll
            for (int nf = 0; nf < 4; ++nf)
                acc[mf][nf] = __builtin_amdgcn_mfma_f32_16x16x32_bf16(
                    af[mf], bfv[nf], acc[mf][nf], 0, 0, 0);
        __syncthreads();
        cur ^= 1;
    }
#undef STAGE_S

    const int c = (blockIdx.y << 1) + wn;  // this wave's class
#pragma unroll
    for (int mf = 0; mf < 4; ++mf) {
        float vj[4];
#pragma unroll
        for (int j = 0; j < 4; ++j) {
            float v = fmaxf(fmaxf(acc[mf][0][j], acc[mf][1][j]),
                            fmaxf(acc[mf][2][j], acc[mf][3][j]));
            v = fmaxf(v, __shfl_xor(v, 1));
            v = fmaxf(v, __shfl_xor(v, 2));
            v = fmaxf(v, __shfl_xor(v, 4));
            v = fmaxf(v, __shfl_xor(v, 8));
            vj[j] = v;
        }
        if ((l & 15) == 0) {
            int rowb = m0 + wm * 64 + mf * 16 + kq * 4;
#pragma unroll
            for (int j = 0; j < 4; ++j) {
                int row = rowb + j;
                int bb = row >> 10, n = row & 1023;
                act[(((size_t)(bb * 20 + c)) << 10) + n] = vj[j];
            }
        }
    }
}

// ---------------------------------------------------------------------------
__global__ __launch_bounds__(256) void logits_max(
    const float* __restrict__ act, const float* __restrict__ lsc,
    float* __restrict__ logits)
{
    const int bc = blockIdx.x;
    const int t  = threadIdx.x;
    float4 v = *(const float4*)(act + ((size_t)bc << 10) + (t << 2));
    float mx = fmaxf(fmaxf(v.x, v.y), fmaxf(v.z, v.w));
#pragma unroll
    for (int off = 32; off >= 1; off >>= 1) mx = fmaxf(mx, __shfl_xor(mx, off));
    __shared__ float wmred[4];
    if ((t & 63) == 0) wmred[t >> 6] = mx;
    __syncthreads();
    if (t == 0) {
        float m2 = fmaxf(fmaxf(wmred[0], wmred[1]), fmaxf(wmred[2], wmred[3]));
        logits[bc] = m2 * lsc[0];
    }
}

// ---------------------------------------------------------------------------
extern "C" void kernel_launch(void* const* d_in, const int* in_sizes, int n_in,
                              void* d_out, int out_size, void* d_ws, size_t ws_size,
                              hipStream_t stream)
{
    const float* pf   = (const float*)d_in[0];
    const float* prot = (const float*)d_in[1];
    const float* w0   = (const float*)d_in[2];
    const float* g0   = (const float*)d_in[3];
    const float* b0   = (const float*)d_in[4];
    const float* m0v  = (const float*)d_in[5];
    const float* v0   = (const float*)d_in[6];
    const float* wr   = (const float*)d_in[7];
    const float* gr   = (const float*)d_in[8];
    const float* br   = (const float*)d_in[9];
    const float* mr   = (const float*)d_in[10];
    const float* vr   = (const float*)d_in[11];
    const float* wl   = (const float*)d_in[12];
    const float* gl   = (const float*)d_in[13];
    const float* bl   = (const float*)d_in[14];
    const float* ml   = (const float*)d_in[15];
    const float* vl   = (const float*)d_in[16];
    const float* wg   = (const float*)d_in[17];
    const float* gG   = (const float*)d_in[18];
    const float* bG   = (const float*)d_in[19];
    const float* mG   = (const float*)d_in[20];
    const float* vG   = (const float*)d_in[21];
    const float* wp   = (const float*)d_in[22];
    const float* gp   = (const float*)d_in[23];
    const float* bp   = (const float*)d_in[24];
    const float* mp   = (const float*)d_in[25];
    const float* vp   = (const float*)d_in[26];
    const float* wf   = (const float*)d_in[27];
    const float* bf_  = (const float*)d_in[28];
    const float* lsc  = (const float*)d_in[29];

    char* ws = (char*)d_ws;
    unsigned short* pf_bf    = (unsigned short*)(ws);             // 25165824 B
    unsigned short* w0_bf    = (unsigned short*)(ws + 25165824);  // 786432
    unsigned short* wr_bf    = (unsigned short*)(ws + 25952256);  // 131072
    unsigned short* wt_bf    = (unsigned short*)(ws + 26083328);  // 589824
    unsigned short* wp_bf    = (unsigned short*)(ws + 26673152);  // 262144
    unsigned short* wf_bf    = (unsigned short*)(ws + 26935296);  // 524288
    unsigned short* prot_bf  = (unsigned short*)(ws + 27459584);  // 1310720
    unsigned short* x1_bf    = (unsigned short*)(ws + 28770304);  // 16777216
    unsigned short* opad     = (unsigned short*)(ws + 45547520);  // 5308416
    unsigned short* lg_bf    = (unsigned short*)(ws + 50855936);  // 8388608
    unsigned short* x2_bf    = (unsigned short*)(ws + 59244544);  // 16777216
    unsigned short* xn_bf    = (unsigned short*)(ws + 76021760);  // 16777216

    float* out    = (float*)d_out;
    float* logits = out;            // [16][20]
    float* act    = out + 320;      // [16][20][1024]
    float* xo     = out + 328000;   // [16384][512] fp32

    // ---- conversions ----
    f2b_kernel<<<6144, 256, 0, stream>>>(pf, pf_bf, 1572864);
    f2b_multi<<<736, 256, 0, stream>>>(w0, wr, wp, wf, prot,
                                       w0_bf, wr_bf, wp_bf, wf_bf, prot_bf);
    convw_kernel<<<1152, 256, 0, stream>>>(wl, wg, wt_bf);
    zero_kernel<<<1296, 256, 0, stream>>>(opad, 331776);

    // ---- adapter: pf x w0^T -> BN -> ReLU -> x1 (bf16) ----
    mfma_gemm<0><<<dim3(128, 4), 256, 0, stream>>>(
        pf_bf, 768, w0_bf, 768, x1_bf, 512, 768,
        g0, b0, m0v, v0, nullptr, 0, nullptr);

    // ---- reduce: x1 x wr^T -> BN -> ReLU -> opad (padded bf16) ----
    mfma_gemm<3><<<dim3(128, 1), 256, 0, stream>>>(
        x1_bf, 512, wr_bf, 512, opad, 0, 512,
        gr, br, mr, vr, nullptr, 0, nullptr);

    // ---- both 3x3 conv branches -> lg (bf16 [16384][256]) ----
    conv_mfma<<<dim3(256, 2), 256, 0, stream>>>(
        opad, wt_bf, gl, bl, ml, vl, gG, bG, mG, vG, lg_bf);

    // ---- project: lg x wp^T -> BN -> +x1 -> ReLU -> x2 (bf16) ----
    mfma_gemm<1><<<dim3(128, 4), 256, 0, stream>>>(
        lg_bf, 256, wp_bf, 256, x2_bf, 512, 256,
        gp, bp, mp, vp, x1_bf, 512, nullptr);

    // ---- final: x2 x wf^T + bf -> xo (fp32 in d_out) ----
    mfma_gemm<2><<<dim3(128, 4), 256, 0, stream>>>(
        x2_bf, 512, wf_bf, 512, xo, 512, 512,
        nullptr, nullptr, nullptr, nullptr, nullptr, 0, bf_);

    // ---- L2 normalize (fp32 in place) + bf16 copy ----
    l2norm_rows<<<4096, 256, 0, stream>>>(xo, xn_bf);

    // ---- sims + max over protos -> act (2 classes / block) ----
    sims_mfma<<<dim3(128, 10), 256, 0, stream>>>(xn_bf, prot_bf, act);

    // ---- logits ----
    logits_max<<<320, 256, 0, stream>>>(act, lsc, logits);
}